// Round 10
// baseline (85.151 us; speedup 1.0000x reference)
//
#include <hip/hip_runtime.h>
#include <hip/hip_bf16.h>
#include <math.h>

#define BB 16
#define CC 128
#define NN 2048
#define CQ 32   // C/4

typedef __attribute__((ext_vector_type(8))) short bf16x8;
typedef __attribute__((ext_vector_type(4))) float f32x4;

__device__ __forceinline__ ushort f2b(float f) {
    __hip_bfloat16 h = __float2bfloat16(f);
    return *reinterpret_cast<ushort*>(&h);
}
__device__ __forceinline__ float b2f(ushort u) {
    union { unsigned u; float f; } v; v.u = ((unsigned)u) << 16;
    return v.f;
}
__device__ __forceinline__ bf16x8 as_b8(uint4 u) {
    union { uint4 u; bf16x8 b; } v; v.u = u; return v.b;
}
__device__ __forceinline__ float fexp2(float x) {
    return __builtin_amdgcn_exp2f(x);   // v_exp_f32: 2^x
}

// ---------------- workspace layout (float granularity offsets) ----------------
// Qt  : bf16 [B][N][32]   off 0          (524,288 fl)   (wq pre-scaled by sqrt(log2 e))
// Vb  : bf16 [B][128][N]  off 524,288    (2,097,152 fl)
// XRb : bf16 [B][128][N]  off 2,621,440  (2,097,152 fl)
// RSI : f32  [B][N]       off 4,718,592  (32,768 fl)
#define OFF_VB  524288
#define OFF_XRB 2621440
#define OFF_RSI 4718592

#define QSCALE 1.2011224087864498f   // sqrt(log2(e)); E comes out scaled by log2(e)

// K1: MFMA projection. Qt[b,n,d] (d<32, scaled), Vb[b,d,n] = wv.x + bv.
__global__ __launch_bounds__(256) void k_proj(const float* __restrict__ x,
        const float* __restrict__ wq, const float* __restrict__ wv,
        const float* __restrict__ bv, ushort* __restrict__ Qt, ushort* __restrict__ Vb) {
    __shared__ ushort Wl[160][136];
    __shared__ ushort Xs[64][136];   // [n][c] bf16
    int bid = (blockIdx.x & 7) * 64 + (blockIdx.x >> 3);   // XCD-chunked swizzle
    int b  = bid >> 5;
    int n0 = (bid & 31) << 6;
    int tid = threadIdx.x;
    #pragma unroll
    for (int k = 0; k < 20; ++k) {
        int idx = k * 256 + tid;          // 5120 float4 chunks = 160x128 f32
        int r = idx >> 5, c4 = (idx & 31) << 2;
        const float* srcw = (r < 32) ? (wq + r * 128 + c4) : (wv + (r - 32) * 128 + c4);
        float4 w4 = *(const float4*)srcw;
        float s = (r < 32) ? QSCALE : 1.0f;
        *(ushort4*)&Wl[r][c4] = make_ushort4(f2b(w4.x * s), f2b(w4.y * s),
                                             f2b(w4.z * s), f2b(w4.w * s));
    }
    const float* xb = x + (size_t)b * CC * NN;
    for (int idx = tid; idx < 2048; idx += 256) {
        int c = idx >> 4, n4 = (idx & 15) << 2;
        float4 xv = *(const float4*)&xb[c * NN + n0 + n4];
        Xs[n4][c]     = f2b(xv.x);
        Xs[n4 + 1][c] = f2b(xv.y);
        Xs[n4 + 2][c] = f2b(xv.z);
        Xs[n4 + 3][c] = f2b(xv.w);
    }
    __syncthreads();
    int w = tid >> 6, l = tid & 63, lr = l & 15, lg = l >> 4;
    f32x4 zero = {0.f, 0.f, 0.f, 0.f};
    int nn = n0 + w * 16 + lr;
    for (int dt = 0; dt < 10; ++dt) {
        f32x4 acc = zero;
        #pragma unroll
        for (int k = 0; k < 4; ++k) {
            bf16x8 a  = *(const bf16x8*)&Wl[dt * 16 + lr][k * 32 + lg * 8];
            bf16x8 bx = *(const bf16x8*)&Xs[w * 16 + lr][k * 32 + lg * 8];
            acc = __builtin_amdgcn_mfma_f32_16x16x32_bf16(a, bx, acc, 0, 0, 0);
        }
        if (dt < 2) {
            ushort4 p = make_ushort4(f2b(acc[0]), f2b(acc[1]), f2b(acc[2]), f2b(acc[3]));
            *(ushort4*)&Qt[(size_t)(b * NN + nn) * CQ + dt * 16 + lg * 4] = p;
        } else {
            #pragma unroll
            for (int i = 0; i < 4; ++i) {
                int vd = (dt - 2) * 16 + lg * 4 + i;
                Vb[(size_t)(b * CC + vd) * NN + nn] = f2b(acc[i] + bv[vd]);
            }
        }
    }
}

// K2: row softmax denominators. E pre-scaled by log2e -> exp2. RSI = 1/rowsum.
__global__ __launch_bounds__(512) void k_rowstats(const ushort* __restrict__ Qt,
        float* __restrict__ RSI) {
    __shared__ ushort Qm[128][36];
    __shared__ float Sred[2][64];
    int bid = (blockIdx.x & 7) * 64 + (blockIdx.x >> 3);
    int b  = bid >> 5;
    int n0 = (bid & 31) << 6;
    int tid = threadIdx.x;
    int w = tid >> 6, l = tid & 63, lr = l & 15, lg = l >> 4;
    int wn = w & 3, wm = w >> 2;
    const ushort* Qtb = Qt + (size_t)b * NN * CQ;
    bf16x8 aq = *(const bf16x8*)&Qtb[(size_t)(n0 + wn * 16 + lr) * CQ + lg * 8];
    int sr = tid >> 2, sc = (tid & 3) * 8;
    uint4 q0 = *(const uint4*)&Qtb[(size_t)sr * CQ + sc];
    float S[4] = {0.f, 0.f, 0.f, 0.f};
    f32x4 zero = {0.f, 0.f, 0.f, 0.f};
    for (int t = 0; t < 16; ++t) {
        __syncthreads();
        *(uint4*)&Qm[sr][sc] = q0;
        __syncthreads();
        if (t < 15)
            q0 = *(const uint4*)&Qtb[(size_t)((t + 1) * 128 + sr) * CQ + sc];
        #pragma unroll
        for (int mi = 0; mi < 4; ++mi) {
            bf16x8 bq = *(const bf16x8*)&Qm[(wm * 4 + mi) * 16 + lr][lg * 8];
            f32x4 e = __builtin_amdgcn_mfma_f32_16x16x32_bf16(aq, bq, zero, 0, 0, 0);
            S[0] += fexp2(e[0]); S[1] += fexp2(e[1]);
            S[2] += fexp2(e[2]); S[3] += fexp2(e[3]);
        }
    }
    #pragma unroll
    for (int d = 1; d < 16; d <<= 1) {
        #pragma unroll
        for (int i = 0; i < 4; ++i) S[i] += __shfl_xor(S[i], d);
    }
    if (lr == 0) {
        #pragma unroll
        for (int i = 0; i < 4; ++i) Sred[wm][wn * 16 + lg * 4 + i] = S[i];
    }
    __syncthreads();
    if (tid < 64)
        RSI[b * NN + n0 + tid] = 1.f / (Sred[0][tid] + Sred[1][tid]);
}

// K3: attn + PV. m-tile 32, NT=64, grid 1024, 512 thr, double-buffered Vs,
// 2 barriers/iter, V(t+1) global loads in flight across the whole iteration.
// Wave (wn=w&3, wm=w>>2) computes one 16x16 E tile; PV: wave owns d-strip 16.
__global__ __launch_bounds__(512, 8) void k_attn_pv(const ushort* __restrict__ Qt,
        const ushort* __restrict__ Vb, const float* __restrict__ RSI,
        ushort* __restrict__ XRb) {
    __shared__ ushort Vs[2][128][68];   // [buf][d][n]  row 136B (8B-aligned)
    __shared__ ushort Ws[32][68];       // [m][n]
    int bid = (blockIdx.x & 7) * 128 + (blockIdx.x >> 3);  // XCD-chunked swizzle
    int b  = bid >> 6;
    int m0 = (bid & 63) << 5;
    int tid = threadIdx.x;
    int w = tid >> 6, l = tid & 63, lr = l & 15, lg = l >> 4;
    int wn = w & 3, wm = w >> 2;
    const ushort* Qtb = Qt + (size_t)b * NN * CQ;
    const ushort* Vbb = Vb + (size_t)b * CC * NN;
    const float*  RSb = RSI + (size_t)b * NN;
    bf16x8 bm = *(const bf16x8*)&Qtb[(size_t)(m0 + wm * 16 + lr) * CQ + lg * 8];
    f32x4 zero = {0.f, 0.f, 0.f, 0.f};
    f32x4 pacc0 = zero, pacc1 = zero;
    float cs = 0.f;
    int dv = tid >> 2, hv = tid & 3;           // stage: row dv, 16-col chunk hv
    const ushort* vsrc = Vbb + (size_t)dv * NN + hv * 16;
    // prologue: tile 0 -> buf 0
    uint4 vr0 = *(const uint4*)(vsrc);
    uint4 vr1 = *(const uint4*)(vsrc + 8);
    bf16x8 aq = *(const bf16x8*)&Qtb[(size_t)(wn * 16 + lr) * CQ + lg * 8];
    {
        ushort* dst = &Vs[0][dv][hv * 16];
        *(uint2*)(dst)      = make_uint2(vr0.x, vr0.y);
        *(uint2*)(dst + 4)  = make_uint2(vr0.z, vr0.w);
        *(uint2*)(dst + 8)  = make_uint2(vr1.x, vr1.y);
        *(uint2*)(dst + 12) = make_uint2(vr1.z, vr1.w);
    }
    for (int t = 0; t < 32; ++t) {
        int cur = t & 1;
        int ntn = ((t + 1) & 31) * 64;         // next tile (wraps harmlessly)
        __syncthreads();                        // A: Vs[cur] ready; prev PV done
        // prefetch tile t+1 (stays in flight until the stores after PV)
        vr0 = *(const uint4*)(vsrc + ntn);
        vr1 = *(const uint4*)(vsrc + ntn + 8);
        bf16x8 aqn = *(const bf16x8*)&Qtb[(size_t)(ntn + wn * 16 + lr) * CQ + lg * 8];
        // ---- E: one 16x16 tile per wave ----
        f32x4 e = __builtin_amdgcn_mfma_f32_16x16x32_bf16(aq, bm, zero, 0, 0, 0);
        int nb = wn * 16 + lg * 4;
        float4 rsi4 = *(const float4*)&RSb[t * 64 + nb];
        float w0 = fexp2(e[0]) * rsi4.x;
        float w1 = fexp2(e[1]) * rsi4.y;
        float w2 = fexp2(e[2]) * rsi4.z;
        float w3 = fexp2(e[3]) * rsi4.w;
        cs += w0 + w1 + w2 + w3;
        *(ushort4*)&Ws[wm * 16 + lr][nb] =
            make_ushort4(f2b(w0), f2b(w1), f2b(w2), f2b(w3));
        __syncthreads();                        // B: Ws ready
        // ---- PV: wave w owns d in [16w,16w+16), K = 64 ----
        #pragma unroll
        for (int kk = 0; kk < 2; ++kk) {
            const ushort* vp = &Vs[cur][w * 16 + lr][kk * 32 + lg * 8];
            uint2 a0 = *(const uint2*)vp;
            uint2 a1 = *(const uint2*)(vp + 4);
            bf16x8 va = as_b8(make_uint4(a0.x, a0.y, a1.x, a1.y));
            const ushort* wp0 = &Ws[lr][kk * 32 + lg * 8];
            uint2 b0 = *(const uint2*)wp0;
            uint2 b1 = *(const uint2*)(wp0 + 4);
            const ushort* wp1 = &Ws[16 + lr][kk * 32 + lg * 8];
            uint2 c0 = *(const uint2*)wp1;
            uint2 c1 = *(const uint2*)(wp1 + 4);
            pacc0 = __builtin_amdgcn_mfma_f32_16x16x32_bf16(
                va, as_b8(make_uint4(b0.x, b0.y, b1.x, b1.y)), pacc0, 0, 0, 0);
            pacc1 = __builtin_amdgcn_mfma_f32_16x16x32_bf16(
                va, as_b8(make_uint4(c0.x, c0.y, c1.x, c1.y)), pacc1, 0, 0, 0);
        }
        // write tile t+1 into the other buffer (no barrier needed here)
        {
            ushort* dst = &Vs[cur ^ 1][dv][hv * 16];
            *(uint2*)(dst)      = make_uint2(vr0.x, vr0.y);
            *(uint2*)(dst + 4)  = make_uint2(vr0.z, vr0.w);
            *(uint2*)(dst + 8)  = make_uint2(vr1.x, vr1.y);
            *(uint2*)(dst + 12) = make_uint2(vr1.z, vr1.w);
        }
        aq = aqn;
    }
    // column sums: shfl over lg, then across the 4 n-strip waves per m-half
    cs += __shfl_xor(cs, 16);
    cs += __shfl_xor(cs, 32);
    __syncthreads();                            // PV done; Ws reusable as scratch
    float* csred = (float*)&Ws[0][0];           // [8][16]
    float* csump = csred + 128;                 // [32]
    if (lg == 0) csred[w * 16 + lr] = cs;
    __syncthreads();
    if (tid < 32) {
        int wmm = tid >> 4;
        float tot = 0.f;
        #pragma unroll
        for (int j = 0; j < 4; ++j) tot += csred[(wmm * 4 + j) * 16 + (tid & 15)];
        csump[tid] = 1.f / (1e-9f + tot);
    }
    __syncthreads();
    float inv0 = csump[lr], inv1 = csump[16 + lr];
    #pragma unroll
    for (int i = 0; i < 4; ++i) {
        int d = w * 16 + lg * 4 + i;
        XRb[(size_t)(b * CC + d) * NN + m0 + lr]      = f2b(pacc0[i] * inv0);
        XRb[(size_t)(b * CC + d) * NN + m0 + 16 + lr] = f2b(pacc1[i] * inv1);
    }
}

// K4: MFMA final: t = wt @ (x - XR); out = x + relu(t*fA + fB).
__global__ __launch_bounds__(256) void k_final(const float* __restrict__ x,
        const ushort* __restrict__ XRb, const float* __restrict__ wt,
        const float* __restrict__ bt, const float* __restrict__ gamma,
        const float* __restrict__ beta, const float* __restrict__ bn_mean,
        const float* __restrict__ bn_var, float* __restrict__ out) {
    __shared__ ushort Wl[128][136];
    __shared__ ushort Us[64][136];   // [n][c] bf16
    __shared__ float fAl[128], fBl[128];
    int bid = (blockIdx.x & 7) * 64 + (blockIdx.x >> 3);
    int b  = bid >> 5;
    int n0 = (bid & 31) << 6;
    int tid = threadIdx.x;
    #pragma unroll
    for (int k = 0; k < 16; ++k) {
        int idx = k * 256 + tid;          // 4096 float4 = 128x128 f32
        int r = idx >> 5, c4 = (idx & 31) << 2;
        float4 w4 = *(const float4*)&wt[r * 128 + c4];
        *(ushort4*)&Wl[r][c4] = make_ushort4(f2b(w4.x), f2b(w4.y), f2b(w4.z), f2b(w4.w));
    }
    if (tid < 128) {
        float A = gamma[tid] * rsqrtf(bn_var[tid] + 1e-5f);
        fAl[tid] = A;
        fBl[tid] = (bt[tid] - bn_mean[tid]) * A + beta[tid];
    }
    const float*  xb  = x   + (size_t)b * CC * NN;
    const ushort* xrb = XRb + (size_t)b * CC * NN;
    for (int idx = tid; idx < 2048; idx += 256) {
        int c = idx >> 4, n4 = (idx & 15) << 2;
        float4 xv = *(const float4*)&xb[c * NN + n0 + n4];
        ushort4 rv = *(const ushort4*)&xrb[c * NN + n0 + n4];
        Us[n4][c]     = f2b(xv.x - b2f(rv.x));
        Us[n4 + 1][c] = f2b(xv.y - b2f(rv.y));
        Us[n4 + 2][c] = f2b(xv.z - b2f(rv.z));
        Us[n4 + 3][c] = f2b(xv.w - b2f(rv.w));
    }
    __syncthreads();
    int w = tid >> 6, l = tid & 63, lr = l & 15, lg = l >> 4;
    f32x4 zero = {0.f, 0.f, 0.f, 0.f};
    int nn = n0 + w * 16 + lr;
    for (int dt = 0; dt < 8; ++dt) {
        f32x4 acc = zero;
        #pragma unroll
        for (int k = 0; k < 4; ++k) {
            bf16x8 a  = *(const bf16x8*)&Wl[dt * 16 + lr][k * 32 + lg * 8];
            bf16x8 bx = *(const bf16x8*)&Us[w * 16 + lr][k * 32 + lg * 8];
            acc = __builtin_amdgcn_mfma_f32_16x16x32_bf16(a, bx, acc, 0, 0, 0);
        }
        #pragma unroll
        for (int i = 0; i < 4; ++i) {
            int r = dt * 16 + lg * 4 + i;
            float t = acc[i] * fAl[r] + fBl[r];
            t = fmaxf(t, 0.f);
            out[(size_t)(b * CC + r) * NN + nn] = xb[r * NN + nn] + t;
        }
    }
}

extern "C" void kernel_launch(void* const* d_in, const int* in_sizes, int n_in,
                              void* d_out, int out_size, void* d_ws, size_t ws_size,
                              hipStream_t stream) {
    const float* x       = (const float*)d_in[0];
    const float* wq      = (const float*)d_in[1];
    const float* wv      = (const float*)d_in[2];
    const float* bv      = (const float*)d_in[3];
    const float* wt      = (const float*)d_in[4];
    const float* bt      = (const float*)d_in[5];
    const float* gamma   = (const float*)d_in[6];
    const float* beta    = (const float*)d_in[7];
    const float* bn_mean = (const float*)d_in[8];
    const float* bn_var  = (const float*)d_in[9];
    float* out = (float*)d_out;
    float* ws  = (float*)d_ws;

    ushort* Qt   = (ushort*)ws;
    ushort* Vbp  = (ushort*)(ws + OFF_VB);
    ushort* XRb  = (ushort*)(ws + OFF_XRB);
    float*  RSI  = ws + OFF_RSI;

    k_proj<<<BB * 32, 256, 0, stream>>>(x, wq, wv, bv, Qt, Vbp);
    k_rowstats<<<BB * 32, 512, 0, stream>>>(Qt, RSI);
    k_attn_pv<<<BB * 64, 512, 0, stream>>>(Qt, Vbp, RSI, XRb);
    k_final<<<BB * 32, 256, 0, stream>>>(x, XRb, wt, bt, gamma, beta, bn_mean, bn_var, out);
}

// Round 11
// 73.578 us; speedup vs baseline: 1.1573x; 1.1573x over previous
//
#include <hip/hip_runtime.h>
#include <hip/hip_bf16.h>
#include <math.h>

#define BB 16
#define CC 128
#define NN 2048
#define CQ 32   // C/4

typedef __attribute__((ext_vector_type(8))) short bf16x8;
typedef __attribute__((ext_vector_type(4))) float f32x4;
typedef __attribute__((ext_vector_type(16))) float f32x16;

__device__ __forceinline__ ushort f2b(float f) {
    __hip_bfloat16 h = __float2bfloat16(f);
    return *reinterpret_cast<ushort*>(&h);
}
__device__ __forceinline__ float b2f(ushort u) {
    union { unsigned u; float f; } v; v.u = ((unsigned)u) << 16;
    return v.f;
}
__device__ __forceinline__ bf16x8 as_b8(uint4 u) {
    union { uint4 u; bf16x8 b; } v; v.u = u; return v.b;
}
__device__ __forceinline__ float fexp2(float x) {
    return __builtin_amdgcn_exp2f(x);   // v_exp_f32: 2^x
}

// ---------------- workspace layout (float granularity offsets) ----------------
// Qt  : bf16 [B][N][32]   off 0          (wq pre-scaled by sqrt(log2 e))
// Vb  : bf16 [B][128][N]  off 524,288
// XRb : bf16 [B][128][N]  off 2,621,440
// RSI : f32  [B][N]       off 4,718,592
#define OFF_VB  524288
#define OFF_XRB 2621440
#define OFF_RSI 4718592

#define QSCALE 1.2011224087864498f   // sqrt(log2(e)); E comes out scaled by log2(e)

// K1: MFMA projection. Qt[b,n,d] (d<32, scaled), Vb[b,d,n] = wv.x + bv.
__global__ __launch_bounds__(256) void k_proj(const float* __restrict__ x,
        const float* __restrict__ wq, const float* __restrict__ wv,
        const float* __restrict__ bv, ushort* __restrict__ Qt, ushort* __restrict__ Vb) {
    __shared__ ushort Wl[160][136];
    __shared__ ushort Xs[64][136];   // [n][c] bf16
    int bid = (blockIdx.x & 7) * 64 + (blockIdx.x >> 3);   // XCD-chunked swizzle
    int b  = bid >> 5;
    int n0 = (bid & 31) << 6;
    int tid = threadIdx.x;
    #pragma unroll
    for (int k = 0; k < 20; ++k) {
        int idx = k * 256 + tid;
        int r = idx >> 5, c4 = (idx & 31) << 2;
        const float* srcw = (r < 32) ? (wq + r * 128 + c4) : (wv + (r - 32) * 128 + c4);
        float4 w4 = *(const float4*)srcw;
        float s = (r < 32) ? QSCALE : 1.0f;
        *(ushort4*)&Wl[r][c4] = make_ushort4(f2b(w4.x * s), f2b(w4.y * s),
                                             f2b(w4.z * s), f2b(w4.w * s));
    }
    const float* xb = x + (size_t)b * CC * NN;
    for (int idx = tid; idx < 2048; idx += 256) {
        int c = idx >> 4, n4 = (idx & 15) << 2;
        float4 xv = *(const float4*)&xb[c * NN + n0 + n4];
        Xs[n4][c]     = f2b(xv.x);
        Xs[n4 + 1][c] = f2b(xv.y);
        Xs[n4 + 2][c] = f2b(xv.z);
        Xs[n4 + 3][c] = f2b(xv.w);
    }
    __syncthreads();
    int w = tid >> 6, l = tid & 63, lr = l & 15, lg = l >> 4;
    f32x4 zero = {0.f, 0.f, 0.f, 0.f};
    int nn = n0 + w * 16 + lr;
    for (int dt = 0; dt < 10; ++dt) {
        f32x4 acc = zero;
        #pragma unroll
        for (int k = 0; k < 4; ++k) {
            bf16x8 a  = *(const bf16x8*)&Wl[dt * 16 + lr][k * 32 + lg * 8];
            bf16x8 bx = *(const bf16x8*)&Xs[w * 16 + lr][k * 32 + lg * 8];
            acc = __builtin_amdgcn_mfma_f32_16x16x32_bf16(a, bx, acc, 0, 0, 0);
        }
        if (dt < 2) {
            ushort4 p = make_ushort4(f2b(acc[0]), f2b(acc[1]), f2b(acc[2]), f2b(acc[3]));
            *(ushort4*)&Qt[(size_t)(b * NN + nn) * CQ + dt * 16 + lg * 4] = p;
        } else {
            #pragma unroll
            for (int i = 0; i < 4; ++i) {
                int vd = (dt - 2) * 16 + lg * 4 + i;
                Vb[(size_t)(b * CC + vd) * NN + nn] = f2b(acc[i] + bv[vd]);
            }
        }
    }
}

// K2: row softmax denominators. E pre-scaled by log2e -> exp2. RSI = 1/rowsum.
__global__ __launch_bounds__(512) void k_rowstats(const ushort* __restrict__ Qt,
        float* __restrict__ RSI) {
    __shared__ ushort Qm[128][36];
    __shared__ float Sred[2][64];
    int bid = (blockIdx.x & 7) * 64 + (blockIdx.x >> 3);
    int b  = bid >> 5;
    int n0 = (bid & 31) << 6;
    int tid = threadIdx.x;
    int w = tid >> 6, l = tid & 63, lr = l & 15, lg = l >> 4;
    int wn = w & 3, wm = w >> 2;
    const ushort* Qtb = Qt + (size_t)b * NN * CQ;
    bf16x8 aq = *(const bf16x8*)&Qtb[(size_t)(n0 + wn * 16 + lr) * CQ + lg * 8];
    int sr = tid >> 2, sc = (tid & 3) * 8;
    uint4 q0 = *(const uint4*)&Qtb[(size_t)sr * CQ + sc];
    float S[4] = {0.f, 0.f, 0.f, 0.f};
    f32x4 zero = {0.f, 0.f, 0.f, 0.f};
    for (int t = 0; t < 16; ++t) {
        __syncthreads();
        *(uint4*)&Qm[sr][sc] = q0;
        __syncthreads();
        if (t < 15)
            q0 = *(const uint4*)&Qtb[(size_t)((t + 1) * 128 + sr) * CQ + sc];
        #pragma unroll
        for (int mi = 0; mi < 4; ++mi) {
            bf16x8 bq = *(const bf16x8*)&Qm[(wm * 4 + mi) * 16 + lr][lg * 8];
            f32x4 e = __builtin_amdgcn_mfma_f32_16x16x32_bf16(aq, bq, zero, 0, 0, 0);
            S[0] += fexp2(e[0]); S[1] += fexp2(e[1]);
            S[2] += fexp2(e[2]); S[3] += fexp2(e[3]);
        }
    }
    #pragma unroll
    for (int d = 1; d < 16; d <<= 1) {
        #pragma unroll
        for (int i = 0; i < 4; ++i) S[i] += __shfl_xor(S[i], d);
    }
    if (lr == 0) {
        #pragma unroll
        for (int i = 0; i < 4; ++i) Sred[wm][wn * 16 + lg * 4 + i] = S[i];
    }
    __syncthreads();
    if (tid < 64)
        RSI[b * NN + n0 + tid] = 1.f / (Sred[0][tid] + Sred[1][tid]);
}

// K3: attn + PV. m-tile 64, NT=64, grid 512, 512 thr, double-buffered Vs,
// 2 barriers/iter. E(16x16): wave (wn=w&3, wm=w>>2), bm[2] in regs, aq global.
// PV(32x32x16): wave (dq=w>>1, mq=w&1) owns 32d x 32m, pacc f32x16.
__global__ __launch_bounds__(512, 4) void k_attn_pv(const ushort* __restrict__ Qt,
        const ushort* __restrict__ Vb, const float* __restrict__ RSI,
        ushort* __restrict__ XRb) {
    __shared__ ushort Vs[2][128][68];   // [buf][d][n]
    __shared__ ushort Ws[64][68];       // [m][n]
    __shared__ float csum[64];
    int bid = (blockIdx.x & 7) * 64 + (blockIdx.x >> 3);   // XCD-chunked swizzle
    int b  = bid >> 5;
    int m0 = (bid & 31) << 6;
    int tid = threadIdx.x;
    int w = tid >> 6, l = tid & 63, lr = l & 15, lg = l >> 4;
    int wn = w & 3, wm = w >> 2;            // E roles
    int ar = l & 31, kh = l >> 5;           // PV lane decode
    int dq = w >> 1, mq = w & 1;            // PV roles
    const ushort* Qtb = Qt + (size_t)b * NN * CQ;
    const ushort* Vbb = Vb + (size_t)b * CC * NN;
    const float*  RSb = RSI + (size_t)b * NN;
    bf16x8 bm0 = *(const bf16x8*)&Qtb[(size_t)(m0 + wm * 32 + lr) * CQ + lg * 8];
    bf16x8 bm1 = *(const bf16x8*)&Qtb[(size_t)(m0 + wm * 32 + 16 + lr) * CQ + lg * 8];
    f32x4 zero = {0.f, 0.f, 0.f, 0.f};
    f32x16 pacc;
    #pragma unroll
    for (int r = 0; r < 16; ++r) pacc[r] = 0.f;
    float cs0 = 0.f, cs1 = 0.f;
    int dv = tid >> 2, hv = tid & 3;        // stage: row dv, 16-col chunk hv
    const ushort* vsrc = Vbb + (size_t)dv * NN + hv * 16;
    // prologue: tile 0 -> buf 0
    uint4 vr0 = *(const uint4*)(vsrc);
    uint4 vr1 = *(const uint4*)(vsrc + 8);
    bf16x8 aq = *(const bf16x8*)&Qtb[(size_t)(wn * 16 + lr) * CQ + lg * 8];
    {
        ushort* dst = &Vs[0][dv][hv * 16];
        *(uint2*)(dst)      = make_uint2(vr0.x, vr0.y);
        *(uint2*)(dst + 4)  = make_uint2(vr0.z, vr0.w);
        *(uint2*)(dst + 8)  = make_uint2(vr1.x, vr1.y);
        *(uint2*)(dst + 12) = make_uint2(vr1.z, vr1.w);
    }
    for (int t = 0; t < 32; ++t) {
        int cur = t & 1;
        int ntn = ((t + 1) & 31) * 64;      // next tile (wraps harmlessly)
        __syncthreads();                     // A: Vs[cur] ready; prev PV done with Ws
        // prefetch tile t+1 (in flight until the stores after PV)
        vr0 = *(const uint4*)(vsrc + ntn);
        vr1 = *(const uint4*)(vsrc + ntn + 8);
        bf16x8 aqn = *(const bf16x8*)&Qtb[(size_t)(ntn + wn * 16 + lr) * CQ + lg * 8];
        // ---- E: 2 tiles per wave ----
        f32x4 e0 = __builtin_amdgcn_mfma_f32_16x16x32_bf16(aq, bm0, zero, 0, 0, 0);
        f32x4 e1 = __builtin_amdgcn_mfma_f32_16x16x32_bf16(aq, bm1, zero, 0, 0, 0);
        int nb = wn * 16 + lg * 4;
        float4 rsi4 = *(const float4*)&RSb[t * 64 + nb];
        {
            float w0 = fexp2(e0[0]) * rsi4.x;
            float w1 = fexp2(e0[1]) * rsi4.y;
            float w2 = fexp2(e0[2]) * rsi4.z;
            float w3 = fexp2(e0[3]) * rsi4.w;
            cs0 += w0 + w1 + w2 + w3;
            *(ushort4*)&Ws[wm * 32 + lr][nb] =
                make_ushort4(f2b(w0), f2b(w1), f2b(w2), f2b(w3));
        }
        {
            float w0 = fexp2(e1[0]) * rsi4.x;
            float w1 = fexp2(e1[1]) * rsi4.y;
            float w2 = fexp2(e1[2]) * rsi4.z;
            float w3 = fexp2(e1[3]) * rsi4.w;
            cs1 += w0 + w1 + w2 + w3;
            *(ushort4*)&Ws[wm * 32 + 16 + lr][nb] =
                make_ushort4(f2b(w0), f2b(w1), f2b(w2), f2b(w3));
        }
        __syncthreads();                     // B: Ws ready
        // ---- PV (32x32x16): wave (dq, mq); K = 64 -> 4 MFMAs ----
        #pragma unroll
        for (int kk = 0; kk < 4; ++kk) {
            const ushort* vp = &Vs[cur][dq * 32 + ar][kk * 16 + kh * 8];
            uint2 a0 = *(const uint2*)vp;
            uint2 a1 = *(const uint2*)(vp + 4);
            const ushort* wp = &Ws[mq * 32 + ar][kk * 16 + kh * 8];
            uint2 b0 = *(const uint2*)wp;
            uint2 b1 = *(const uint2*)(wp + 4);
            pacc = __builtin_amdgcn_mfma_f32_32x32x16_bf16(
                as_b8(make_uint4(a0.x, a0.y, a1.x, a1.y)),
                as_b8(make_uint4(b0.x, b0.y, b1.x, b1.y)), pacc, 0, 0, 0);
        }
        // write tile t+1 into the other buffer
        {
            ushort* dst = &Vs[cur ^ 1][dv][hv * 16];
            *(uint2*)(dst)      = make_uint2(vr0.x, vr0.y);
            *(uint2*)(dst + 4)  = make_uint2(vr0.z, vr0.w);
            *(uint2*)(dst + 8)  = make_uint2(vr1.x, vr1.y);
            *(uint2*)(dst + 12) = make_uint2(vr1.z, vr1.w);
        }
        aq = aqn;
    }
    // column sums: shfl over lg, then across 4 wn waves via LDS (alias Ws)
    cs0 += __shfl_xor(cs0, 16); cs0 += __shfl_xor(cs0, 32);
    cs1 += __shfl_xor(cs1, 16); cs1 += __shfl_xor(cs1, 32);
    __syncthreads();                         // PV done; Ws reusable as scratch
    float* csred = (float*)&Ws[0][0];        // [4][64]
    if (lg == 0) {
        csred[wn * 64 + wm * 32 + lr]      = cs0;
        csred[wn * 64 + wm * 32 + 16 + lr] = cs1;
    }
    __syncthreads();
    if (tid < 64) {
        float tot = csred[tid] + csred[64 + tid] + csred[128 + tid] + csred[192 + tid];
        csum[tid] = 1.f / (1e-9f + tot);
    }
    __syncthreads();
    float inv = csum[mq * 32 + ar];
    int m = m0 + mq * 32 + ar;
    #pragma unroll
    for (int r = 0; r < 16; ++r) {
        int d = dq * 32 + (r & 3) + 8 * (r >> 2) + 4 * kh;
        XRb[(size_t)(b * CC + d) * NN + m] = f2b(pacc[r] * inv);
    }
}

// K4: MFMA final: t = wt @ (x - XR); out = x + relu(t*fA + fB).
__global__ __launch_bounds__(256) void k_final(const float* __restrict__ x,
        const ushort* __restrict__ XRb, const float* __restrict__ wt,
        const float* __restrict__ bt, const float* __restrict__ gamma,
        const float* __restrict__ beta, const float* __restrict__ bn_mean,
        const float* __restrict__ bn_var, float* __restrict__ out) {
    __shared__ ushort Wl[128][136];
    __shared__ ushort Us[64][136];   // [n][c] bf16
    __shared__ float fAl[128], fBl[128];
    int bid = (blockIdx.x & 7) * 64 + (blockIdx.x >> 3);
    int b  = bid >> 5;
    int n0 = (bid & 31) << 6;
    int tid = threadIdx.x;
    #pragma unroll
    for (int k = 0; k < 16; ++k) {
        int idx = k * 256 + tid;
        int r = idx >> 5, c4 = (idx & 31) << 2;
        float4 w4 = *(const float4*)&wt[r * 128 + c4];
        *(ushort4*)&Wl[r][c4] = make_ushort4(f2b(w4.x), f2b(w4.y), f2b(w4.z), f2b(w4.w));
    }
    if (tid < 128) {
        float A = gamma[tid] * rsqrtf(bn_var[tid] + 1e-5f);
        fAl[tid] = A;
        fBl[tid] = (bt[tid] - bn_mean[tid]) * A + beta[tid];
    }
    const float*  xb  = x   + (size_t)b * CC * NN;
    const ushort* xrb = XRb + (size_t)b * CC * NN;
    for (int idx = tid; idx < 2048; idx += 256) {
        int c = idx >> 4, n4 = (idx & 15) << 2;
        float4 xv = *(const float4*)&xb[c * NN + n0 + n4];
        ushort4 rv = *(const ushort4*)&xrb[c * NN + n0 + n4];
        Us[n4][c]     = f2b(xv.x - b2f(rv.x));
        Us[n4 + 1][c] = f2b(xv.y - b2f(rv.y));
        Us[n4 + 2][c] = f2b(xv.z - b2f(rv.z));
        Us[n4 + 3][c] = f2b(xv.w - b2f(rv.w));
    }
    __syncthreads();
    int w = tid >> 6, l = tid & 63, lr = l & 15, lg = l >> 4;
    f32x4 zero = {0.f, 0.f, 0.f, 0.f};
    int nn = n0 + w * 16 + lr;
    for (int dt = 0; dt < 8; ++dt) {
        f32x4 acc = zero;
        #pragma unroll
        for (int k = 0; k < 4; ++k) {
            bf16x8 a  = *(const bf16x8*)&Wl[dt * 16 + lr][k * 32 + lg * 8];
            bf16x8 bx = *(const bf16x8*)&Us[w * 16 + lr][k * 32 + lg * 8];
            acc = __builtin_amdgcn_mfma_f32_16x16x32_bf16(a, bx, acc, 0, 0, 0);
        }
        #pragma unroll
        for (int i = 0; i < 4; ++i) {
            int r = dt * 16 + lg * 4 + i;
            float t = acc[i] * fAl[r] + fBl[r];
            t = fmaxf(t, 0.f);
            out[(size_t)(b * CC + r) * NN + nn] = xb[r * NN + nn] + t;
        }
    }
}

extern "C" void kernel_launch(void* const* d_in, const int* in_sizes, int n_in,
                              void* d_out, int out_size, void* d_ws, size_t ws_size,
                              hipStream_t stream) {
    const float* x       = (const float*)d_in[0];
    const float* wq      = (const float*)d_in[1];
    const float* wv      = (const float*)d_in[2];
    const float* bv      = (const float*)d_in[3];
    const float* wt      = (const float*)d_in[4];
    const float* bt      = (const float*)d_in[5];
    const float* gamma   = (const float*)d_in[6];
    const float* beta    = (const float*)d_in[7];
    const float* bn_mean = (const float*)d_in[8];
    const float* bn_var  = (const float*)d_in[9];
    float* out = (float*)d_out;
    float* ws  = (float*)d_ws;

    ushort* Qt   = (ushort*)ws;
    ushort* Vbp  = (ushort*)(ws + OFF_VB);
    ushort* XRb  = (ushort*)(ws + OFF_XRB);
    float*  RSI  = ws + OFF_RSI;

    k_proj<<<BB * 32, 256, 0, stream>>>(x, wq, wv, bv, Qt, Vbp);
    k_rowstats<<<BB * 32, 512, 0, stream>>>(Qt, RSI);
    k_attn_pv<<<BB * 32, 512, 0, stream>>>(Qt, Vbp, RSI, XRb);
    k_final<<<BB * 32, 256, 0, stream>>>(x, XRb, wt, bt, gamma, beta, bn_mean, bn_var, out);
}

// Round 12
// 70.445 us; speedup vs baseline: 1.2088x; 1.0445x over previous
//
#include <hip/hip_runtime.h>
#include <hip/hip_bf16.h>
#include <math.h>

#define BB 16
#define CC 128
#define NN 2048
#define CQ 32   // C/4

typedef __attribute__((ext_vector_type(8))) short bf16x8;
typedef __attribute__((ext_vector_type(4))) float f32x4;
typedef __attribute__((ext_vector_type(16))) float f32x16;

__device__ __forceinline__ ushort f2b(float f) {
    __hip_bfloat16 h = __float2bfloat16(f);
    return *reinterpret_cast<ushort*>(&h);
}
__device__ __forceinline__ float b2f(ushort u) {
    union { unsigned u; float f; } v; v.u = ((unsigned)u) << 16;
    return v.f;
}
__device__ __forceinline__ bf16x8 as_b8(uint4 u) {
    union { uint4 u; bf16x8 b; } v; v.u = u; return v.b;
}
__device__ __forceinline__ float fexp2(float x) {
    return __builtin_amdgcn_exp2f(x);   // v_exp_f32: 2^x
}

// ---------------- workspace layout (float granularity offsets) ----------------
// Qt  : bf16 [B][N][32]   off 0          (wq pre-scaled by sqrt(log2 e))
// Vb  : bf16 [B][128][N]  off 524,288
// XRb : bf16 [B][128][N]  off 2,621,440
// RSI : f32  [B][N]       off 4,718,592
#define OFF_VB  524288
#define OFF_XRB 2621440
#define OFF_RSI 4718592

#define QSCALE 1.2011224087864498f   // sqrt(log2(e)); E comes out scaled by log2(e)

// K1: MFMA projection. Qt[b,n,d] (d<32, scaled), Vb[b,d,n] = wv.x + bv.
__global__ __launch_bounds__(256) void k_proj(const float* __restrict__ x,
        const float* __restrict__ wq, const float* __restrict__ wv,
        const float* __restrict__ bv, ushort* __restrict__ Qt, ushort* __restrict__ Vb) {
    __shared__ ushort Wl[160][136];
    __shared__ ushort Xs[64][136];   // [n][c] bf16
    int bid = (blockIdx.x & 7) * 64 + (blockIdx.x >> 3);   // XCD-chunked swizzle
    int b  = bid >> 5;
    int n0 = (bid & 31) << 6;
    int tid = threadIdx.x;
    #pragma unroll
    for (int k = 0; k < 20; ++k) {
        int idx = k * 256 + tid;
        int r = idx >> 5, c4 = (idx & 31) << 2;
        const float* srcw = (r < 32) ? (wq + r * 128 + c4) : (wv + (r - 32) * 128 + c4);
        float4 w4 = *(const float4*)srcw;
        float s = (r < 32) ? QSCALE : 1.0f;
        *(ushort4*)&Wl[r][c4] = make_ushort4(f2b(w4.x * s), f2b(w4.y * s),
                                             f2b(w4.z * s), f2b(w4.w * s));
    }
    const float* xb = x + (size_t)b * CC * NN;
    for (int idx = tid; idx < 2048; idx += 256) {
        int c = idx >> 4, n4 = (idx & 15) << 2;
        float4 xv = *(const float4*)&xb[c * NN + n0 + n4];
        Xs[n4][c]     = f2b(xv.x);
        Xs[n4 + 1][c] = f2b(xv.y);
        Xs[n4 + 2][c] = f2b(xv.z);
        Xs[n4 + 3][c] = f2b(xv.w);
    }
    __syncthreads();
    int w = tid >> 6, l = tid & 63, lr = l & 15, lg = l >> 4;
    f32x4 zero = {0.f, 0.f, 0.f, 0.f};
    int nn = n0 + w * 16 + lr;
    for (int dt = 0; dt < 10; ++dt) {
        f32x4 acc = zero;
        #pragma unroll
        for (int k = 0; k < 4; ++k) {
            bf16x8 a  = *(const bf16x8*)&Wl[dt * 16 + lr][k * 32 + lg * 8];
            bf16x8 bx = *(const bf16x8*)&Xs[w * 16 + lr][k * 32 + lg * 8];
            acc = __builtin_amdgcn_mfma_f32_16x16x32_bf16(a, bx, acc, 0, 0, 0);
        }
        if (dt < 2) {
            ushort4 p = make_ushort4(f2b(acc[0]), f2b(acc[1]), f2b(acc[2]), f2b(acc[3]));
            *(ushort4*)&Qt[(size_t)(b * NN + nn) * CQ + dt * 16 + lg * 4] = p;
        } else {
            #pragma unroll
            for (int i = 0; i < 4; ++i) {
                int vd = (dt - 2) * 16 + lg * 4 + i;
                Vb[(size_t)(b * CC + vd) * NN + nn] = f2b(acc[i] + bv[vd]);
            }
        }
    }
}

// K2: row softmax denominators. E pre-scaled by log2e -> exp2. RSI = 1/rowsum.
__global__ __launch_bounds__(512) void k_rowstats(const ushort* __restrict__ Qt,
        float* __restrict__ RSI) {
    __shared__ ushort Qm[128][36];
    __shared__ float Sred[2][64];
    int bid = (blockIdx.x & 7) * 64 + (blockIdx.x >> 3);
    int b  = bid >> 5;
    int n0 = (bid & 31) << 6;
    int tid = threadIdx.x;
    int w = tid >> 6, l = tid & 63, lr = l & 15, lg = l >> 4;
    int wn = w & 3, wm = w >> 2;
    const ushort* Qtb = Qt + (size_t)b * NN * CQ;
    bf16x8 aq = *(const bf16x8*)&Qtb[(size_t)(n0 + wn * 16 + lr) * CQ + lg * 8];
    int sr = tid >> 2, sc = (tid & 3) * 8;
    uint4 q0 = *(const uint4*)&Qtb[(size_t)sr * CQ + sc];
    float S[4] = {0.f, 0.f, 0.f, 0.f};
    f32x4 zero = {0.f, 0.f, 0.f, 0.f};
    for (int t = 0; t < 16; ++t) {
        __syncthreads();
        *(uint4*)&Qm[sr][sc] = q0;
        __syncthreads();
        if (t < 15)
            q0 = *(const uint4*)&Qtb[(size_t)((t + 1) * 128 + sr) * CQ + sc];
        #pragma unroll
        for (int mi = 0; mi < 4; ++mi) {
            bf16x8 bq = *(const bf16x8*)&Qm[(wm * 4 + mi) * 16 + lr][lg * 8];
            f32x4 e = __builtin_amdgcn_mfma_f32_16x16x32_bf16(aq, bq, zero, 0, 0, 0);
            S[0] += fexp2(e[0]); S[1] += fexp2(e[1]);
            S[2] += fexp2(e[2]); S[3] += fexp2(e[3]);
        }
    }
    #pragma unroll
    for (int d = 1; d < 16; d <<= 1) {
        #pragma unroll
        for (int i = 0; i < 4; ++i) S[i] += __shfl_xor(S[i], d);
    }
    if (lr == 0) {
        #pragma unroll
        for (int i = 0; i < 4; ++i) Sred[wm][wn * 16 + lg * 4 + i] = S[i];
    }
    __syncthreads();
    if (tid < 64)
        RSI[b * NN + n0 + tid] = 1.f / (Sred[0][tid] + Sred[1][tid]);
}

// K3: attn + PV, producer/consumer wave specialization.
// m-tile 64, NT=64, grid 512, 512 thr. Waves 0-3 (producers): E(t+1) + softmax
// + Ws write + V(t+1) staging. Waves 4-7 (consumers): PV(32x32x16) on tile t.
// Vs/Ws double-buffered; ONE barrier per iteration.
__global__ __launch_bounds__(512, 4) void k_attn_pv(const ushort* __restrict__ Qt,
        const ushort* __restrict__ Vb, const float* __restrict__ RSI,
        ushort* __restrict__ XRb) {
    __shared__ ushort Vs[2][128][68];   // [buf][d][n]
    __shared__ ushort Ws[2][64][68];    // [buf][m][n]
    __shared__ float csred[4][64];
    __shared__ float csum[64];
    int bid = (blockIdx.x & 7) * 64 + (blockIdx.x >> 3);   // XCD-chunked swizzle
    int b  = bid >> 5;
    int m0 = (bid & 31) << 6;
    int tid = threadIdx.x;
    int w = tid >> 6, l = tid & 63, lr = l & 15, lg = l >> 4;
    const ushort* Qtb = Qt + (size_t)b * NN * CQ;
    const ushort* Vbb = Vb + (size_t)b * CC * NN;
    const float*  RSb = RSI + (size_t)b * NN;
    f32x4 zero = {0.f, 0.f, 0.f, 0.f};
    bool producer = (w < 4);

    // ---------------- producer state ----------------
    bf16x8 bm[4];
    float cs[4] = {0.f, 0.f, 0.f, 0.f};
    int sv = 0, shv = 0;
    const ushort* vsrc = nullptr;
    bf16x8 aq_nx; float4 rsi_nx;
    // ---------------- consumer state ----------------
    f32x16 pacc0, pacc1;
    int ar = l & 31, kh = l >> 5, dq = w - 4;

    if (producer) {
        #pragma unroll
        for (int mi = 0; mi < 4; ++mi)
            bm[mi] = *(const bf16x8*)&Qtb[(size_t)(m0 + mi * 16 + lr) * CQ + lg * 8];
        sv = tid >> 1; shv = (tid & 1) * 32;        // V row, 32-col half
        vsrc = Vbb + (size_t)sv * NN + shv;
        // ---- stage V(0) -> Vs[0] ----
        {
            uint4 v0 = *(const uint4*)(vsrc);
            uint4 v1 = *(const uint4*)(vsrc + 8);
            uint4 v2 = *(const uint4*)(vsrc + 16);
            uint4 v3 = *(const uint4*)(vsrc + 24);
            ushort* dst = &Vs[0][sv][shv];
            *(uint2*)(dst)      = make_uint2(v0.x, v0.y);
            *(uint2*)(dst + 4)  = make_uint2(v0.z, v0.w);
            *(uint2*)(dst + 8)  = make_uint2(v1.x, v1.y);
            *(uint2*)(dst + 12) = make_uint2(v1.z, v1.w);
            *(uint2*)(dst + 16) = make_uint2(v2.x, v2.y);
            *(uint2*)(dst + 20) = make_uint2(v2.z, v2.w);
            *(uint2*)(dst + 24) = make_uint2(v3.x, v3.y);
            *(uint2*)(dst + 28) = make_uint2(v3.z, v3.w);
        }
        // ---- E(0) -> Ws[0] ----
        {
            bf16x8 aq0 = *(const bf16x8*)&Qtb[(size_t)(w * 16 + lr) * CQ + lg * 8];
            float4 r4 = *(const float4*)&RSb[w * 16 + lg * 4];
            int nb = w * 16 + lg * 4;
            #pragma unroll
            for (int mi = 0; mi < 4; ++mi) {
                f32x4 e = __builtin_amdgcn_mfma_f32_16x16x32_bf16(aq0, bm[mi], zero, 0, 0, 0);
                float w0 = fexp2(e[0]) * r4.x;
                float w1 = fexp2(e[1]) * r4.y;
                float w2 = fexp2(e[2]) * r4.z;
                float w3 = fexp2(e[3]) * r4.w;
                cs[mi] += w0 + w1 + w2 + w3;
                *(ushort4*)&Ws[0][mi * 16 + lr][nb] =
                    make_ushort4(f2b(w0), f2b(w1), f2b(w2), f2b(w3));
            }
        }
        // prefetch operands for tile 1
        aq_nx  = *(const bf16x8*)&Qtb[(size_t)(64 + w * 16 + lr) * CQ + lg * 8];
        rsi_nx = *(const float4*)&RSb[64 + w * 16 + lg * 4];
    } else {
        #pragma unroll
        for (int r = 0; r < 16; ++r) { pacc0[r] = 0.f; pacc1[r] = 0.f; }
    }
    __syncthreads();
    for (int t = 0; t < 32; ++t) {
        int cur = t & 1;
        if (producer) {
            if (t < 31) {
                int ntn = (t + 1) * 64;
                // issue V(t+1) global loads (in flight under E+exp)
                uint4 v0 = *(const uint4*)(vsrc + ntn);
                uint4 v1 = *(const uint4*)(vsrc + ntn + 8);
                uint4 v2 = *(const uint4*)(vsrc + ntn + 16);
                uint4 v3 = *(const uint4*)(vsrc + ntn + 24);
                bf16x8 aq = aq_nx;
                float4 r4 = rsi_nx;
                if (t < 30) {
                    int nt2 = (t + 2) * 64;
                    aq_nx  = *(const bf16x8*)&Qtb[(size_t)(nt2 + w * 16 + lr) * CQ + lg * 8];
                    rsi_nx = *(const float4*)&RSb[nt2 + w * 16 + lg * 4];
                }
                // ---- E(t+1) -> Ws[cur^1] ----
                int nb = w * 16 + lg * 4;
                #pragma unroll
                for (int mi = 0; mi < 4; ++mi) {
                    f32x4 e = __builtin_amdgcn_mfma_f32_16x16x32_bf16(aq, bm[mi], zero, 0, 0, 0);
                    float w0 = fexp2(e[0]) * r4.x;
                    float w1 = fexp2(e[1]) * r4.y;
                    float w2 = fexp2(e[2]) * r4.z;
                    float w3 = fexp2(e[3]) * r4.w;
                    cs[mi] += w0 + w1 + w2 + w3;
                    *(ushort4*)&Ws[cur ^ 1][mi * 16 + lr][nb] =
                        make_ushort4(f2b(w0), f2b(w1), f2b(w2), f2b(w3));
                }
                // ---- write V(t+1) -> Vs[cur^1] ----
                ushort* dst = &Vs[cur ^ 1][sv][shv];
                *(uint2*)(dst)      = make_uint2(v0.x, v0.y);
                *(uint2*)(dst + 4)  = make_uint2(v0.z, v0.w);
                *(uint2*)(dst + 8)  = make_uint2(v1.x, v1.y);
                *(uint2*)(dst + 12) = make_uint2(v1.z, v1.w);
                *(uint2*)(dst + 16) = make_uint2(v2.x, v2.y);
                *(uint2*)(dst + 20) = make_uint2(v2.z, v2.w);
                *(uint2*)(dst + 24) = make_uint2(v3.x, v3.y);
                *(uint2*)(dst + 28) = make_uint2(v3.z, v3.w);
            }
        } else {
            // ---- PV on tile t: wave dq owns d [32dq, 32dq+32), m 0..63 ----
            __builtin_amdgcn_s_setprio(1);
            #pragma unroll
            for (int kk = 0; kk < 4; ++kk) {
                const ushort* vp = &Vs[cur][dq * 32 + ar][kk * 16 + kh * 8];
                uint2 a0 = *(const uint2*)vp;
                uint2 a1 = *(const uint2*)(vp + 4);
                bf16x8 va = as_b8(make_uint4(a0.x, a0.y, a1.x, a1.y));
                const ushort* wp0 = &Ws[cur][ar][kk * 16 + kh * 8];
                uint2 b0 = *(const uint2*)wp0;
                uint2 b1 = *(const uint2*)(wp0 + 4);
                const ushort* wp1 = &Ws[cur][32 + ar][kk * 16 + kh * 8];
                uint2 c0 = *(const uint2*)wp1;
                uint2 c1 = *(const uint2*)(wp1 + 4);
                pacc0 = __builtin_amdgcn_mfma_f32_32x32x16_bf16(
                    va, as_b8(make_uint4(b0.x, b0.y, b1.x, b1.y)), pacc0, 0, 0, 0);
                pacc1 = __builtin_amdgcn_mfma_f32_32x32x16_bf16(
                    va, as_b8(make_uint4(c0.x, c0.y, c1.x, c1.y)), pacc1, 0, 0, 0);
            }
            __builtin_amdgcn_s_setprio(0);
        }
        __syncthreads();
    }
    // ---- colsum reduce (producers hold cs) ----
    if (producer) {
        #pragma unroll
        for (int mi = 0; mi < 4; ++mi) {
            cs[mi] += __shfl_xor(cs[mi], 16);
            cs[mi] += __shfl_xor(cs[mi], 32);
        }
        if (lg == 0) {
            #pragma unroll
            for (int mi = 0; mi < 4; ++mi) csred[w][mi * 16 + lr] = cs[mi];
        }
    }
    __syncthreads();
    if (tid < 64) {
        float tot = csred[0][tid] + csred[1][tid] + csred[2][tid] + csred[3][tid];
        csum[tid] = 1.f / (1e-9f + tot);
    }
    __syncthreads();
    if (!producer) {
        float inv0 = csum[ar], inv1 = csum[32 + ar];
        #pragma unroll
        for (int r = 0; r < 16; ++r) {
            int d = dq * 32 + (r & 3) + 8 * (r >> 2) + 4 * kh;
            XRb[(size_t)(b * CC + d) * NN + m0 + ar]      = f2b(pacc0[r] * inv0);
            XRb[(size_t)(b * CC + d) * NN + m0 + 32 + ar] = f2b(pacc1[r] * inv1);
        }
    }
}

// K4: MFMA final: t = wt @ (x - XR); out = x + relu(t*fA + fB).
__global__ __launch_bounds__(256) void k_final(const float* __restrict__ x,
        const ushort* __restrict__ XRb, const float* __restrict__ wt,
        const float* __restrict__ bt, const float* __restrict__ gamma,
        const float* __restrict__ beta, const float* __restrict__ bn_mean,
        const float* __restrict__ bn_var, float* __restrict__ out) {
    __shared__ ushort Wl[128][136];
    __shared__ ushort Us[64][136];   // [n][c] bf16
    __shared__ float fAl[128], fBl[128];
    int bid = (blockIdx.x & 7) * 64 + (blockIdx.x >> 3);
    int b  = bid >> 5;
    int n0 = (bid & 31) << 6;
    int tid = threadIdx.x;
    #pragma unroll
    for (int k = 0; k < 16; ++k) {
        int idx = k * 256 + tid;
        int r = idx >> 5, c4 = (idx & 31) << 2;
        float4 w4 = *(const float4*)&wt[r * 128 + c4];
        *(ushort4*)&Wl[r][c4] = make_ushort4(f2b(w4.x), f2b(w4.y), f2b(w4.z), f2b(w4.w));
    }
    if (tid < 128) {
        float A = gamma[tid] * rsqrtf(bn_var[tid] + 1e-5f);
        fAl[tid] = A;
        fBl[tid] = (bt[tid] - bn_mean[tid]) * A + beta[tid];
    }
    const float*  xb  = x   + (size_t)b * CC * NN;
    const ushort* xrb = XRb + (size_t)b * CC * NN;
    for (int idx = tid; idx < 2048; idx += 256) {
        int c = idx >> 4, n4 = (idx & 15) << 2;
        float4 xv = *(const float4*)&xb[c * NN + n0 + n4];
        ushort4 rv = *(const ushort4*)&xrb[c * NN + n0 + n4];
        Us[n4][c]     = f2b(xv.x - b2f(rv.x));
        Us[n4 + 1][c] = f2b(xv.y - b2f(rv.y));
        Us[n4 + 2][c] = f2b(xv.z - b2f(rv.z));
        Us[n4 + 3][c] = f2b(xv.w - b2f(rv.w));
    }
    __syncthreads();
    int w = tid >> 6, l = tid & 63, lr = l & 15, lg = l >> 4;
    f32x4 zero = {0.f, 0.f, 0.f, 0.f};
    int nn = n0 + w * 16 + lr;
    for (int dt = 0; dt < 8; ++dt) {
        f32x4 acc = zero;
        #pragma unroll
        for (int k = 0; k < 4; ++k) {
            bf16x8 a  = *(const bf16x8*)&Wl[dt * 16 + lr][k * 32 + lg * 8];
            bf16x8 bx = *(const bf16x8*)&Us[w * 16 + lr][k * 32 + lg * 8];
            acc = __builtin_amdgcn_mfma_f32_16x16x32_bf16(a, bx, acc, 0, 0, 0);
        }
        #pragma unroll
        for (int i = 0; i < 4; ++i) {
            int r = dt * 16 + lg * 4 + i;
            float t = acc[i] * fAl[r] + fBl[r];
            t = fmaxf(t, 0.f);
            out[(size_t)(b * CC + r) * NN + nn] = xb[r * NN + nn] + t;
        }
    }
}

extern "C" void kernel_launch(void* const* d_in, const int* in_sizes, int n_in,
                              void* d_out, int out_size, void* d_ws, size_t ws_size,
                              hipStream_t stream) {
    const float* x       = (const float*)d_in[0];
    const float* wq      = (const float*)d_in[1];
    const float* wv      = (const float*)d_in[2];
    const float* bv      = (const float*)d_in[3];
    const float* wt      = (const float*)d_in[4];
    const float* bt      = (const float*)d_in[5];
    const float* gamma   = (const float*)d_in[6];
    const float* beta    = (const float*)d_in[7];
    const float* bn_mean = (const float*)d_in[8];
    const float* bn_var  = (const float*)d_in[9];
    float* out = (float*)d_out;
    float* ws  = (float*)d_ws;

    ushort* Qt   = (ushort*)ws;
    ushort* Vbp  = (ushort*)(ws + OFF_VB);
    ushort* XRb  = (ushort*)(ws + OFF_XRB);
    float*  RSI  = ws + OFF_RSI;

    k_proj<<<BB * 32, 256, 0, stream>>>(x, wq, wv, bv, Qt, Vbp);
    k_rowstats<<<BB * 32, 512, 0, stream>>>(Qt, RSI);
    k_attn_pv<<<BB * 32, 512, 0, stream>>>(Qt, Vbp, RSI, XRb);
    k_final<<<BB * 32, 256, 0, stream>>>(x, XRb, wt, bt, gamma, beta, bn_mean, bn_var, out);
}

// Round 13
// 66.983 us; speedup vs baseline: 1.2712x; 1.0517x over previous
//
#include <hip/hip_runtime.h>
#include <hip/hip_bf16.h>
#include <math.h>

#define BB 16
#define CC 128
#define NN 2048
#define CQ 32   // C/4

typedef __attribute__((ext_vector_type(8))) short bf16x8;
typedef __attribute__((ext_vector_type(4))) float f32x4;
typedef __attribute__((ext_vector_type(16))) float f32x16;

__device__ __forceinline__ ushort f2b(float f) {
    __hip_bfloat16 h = __float2bfloat16(f);
    return *reinterpret_cast<ushort*>(&h);
}
__device__ __forceinline__ float b2f(ushort u) {
    union { unsigned u; float f; } v; v.u = ((unsigned)u) << 16;
    return v.f;
}
__device__ __forceinline__ bf16x8 as_b8(uint4 u) {
    union { uint4 u; bf16x8 b; } v; v.u = u; return v.b;
}
__device__ __forceinline__ float fexp2(float x) {
    return __builtin_amdgcn_exp2f(x);   // v_exp_f32: 2^x
}

// ---------------- workspace layout (float granularity offsets) ----------------
// Qt  : bf16 [B][N][32]   off 0          (wq pre-scaled by sqrt(log2 e))
// Vb  : bf16 [B][128][N]  off 524,288
// XRb : bf16 [B][128][N]  off 2,621,440
// RSI : f32  [B][N]       off 4,718,592
#define OFF_VB  524288
#define OFF_XRB 2621440
#define OFF_RSI 4718592

#define QSCALE 1.2011224087864498f   // sqrt(log2(e)); E comes out scaled by log2(e)

// K1: MFMA projection. Qt[b,n,d] (d<32, scaled), Vb[b,d,n] = wv.x + bv.
__global__ __launch_bounds__(256) void k_proj(const float* __restrict__ x,
        const float* __restrict__ wq, const float* __restrict__ wv,
        const float* __restrict__ bv, ushort* __restrict__ Qt, ushort* __restrict__ Vb) {
    __shared__ ushort Wl[160][136];
    __shared__ ushort Xs[64][136];   // [n][c] bf16
    int bid = (blockIdx.x & 7) * 64 + (blockIdx.x >> 3);   // XCD-chunked swizzle
    int b  = bid >> 5;
    int n0 = (bid & 31) << 6;
    int tid = threadIdx.x;
    #pragma unroll
    for (int k = 0; k < 20; ++k) {
        int idx = k * 256 + tid;
        int r = idx >> 5, c4 = (idx & 31) << 2;
        const float* srcw = (r < 32) ? (wq + r * 128 + c4) : (wv + (r - 32) * 128 + c4);
        float4 w4 = *(const float4*)srcw;
        float s = (r < 32) ? QSCALE : 1.0f;
        *(ushort4*)&Wl[r][c4] = make_ushort4(f2b(w4.x * s), f2b(w4.y * s),
                                             f2b(w4.z * s), f2b(w4.w * s));
    }
    const float* xb = x + (size_t)b * CC * NN;
    for (int idx = tid; idx < 2048; idx += 256) {
        int c = idx >> 4, n4 = (idx & 15) << 2;
        float4 xv = *(const float4*)&xb[c * NN + n0 + n4];
        Xs[n4][c]     = f2b(xv.x);
        Xs[n4 + 1][c] = f2b(xv.y);
        Xs[n4 + 2][c] = f2b(xv.z);
        Xs[n4 + 3][c] = f2b(xv.w);
    }
    __syncthreads();
    int w = tid >> 6, l = tid & 63, lr = l & 15, lg = l >> 4;
    f32x4 zero = {0.f, 0.f, 0.f, 0.f};
    int nn = n0 + w * 16 + lr;
    for (int dt = 0; dt < 10; ++dt) {
        f32x4 acc = zero;
        #pragma unroll
        for (int k = 0; k < 4; ++k) {
            bf16x8 a  = *(const bf16x8*)&Wl[dt * 16 + lr][k * 32 + lg * 8];
            bf16x8 bx = *(const bf16x8*)&Xs[w * 16 + lr][k * 32 + lg * 8];
            acc = __builtin_amdgcn_mfma_f32_16x16x32_bf16(a, bx, acc, 0, 0, 0);
        }
        if (dt < 2) {
            ushort4 p = make_ushort4(f2b(acc[0]), f2b(acc[1]), f2b(acc[2]), f2b(acc[3]));
            *(ushort4*)&Qt[(size_t)(b * NN + nn) * CQ + dt * 16 + lg * 4] = p;
        } else {
            #pragma unroll
            for (int i = 0; i < 4; ++i) {
                int vd = (dt - 2) * 16 + lg * 4 + i;
                Vb[(size_t)(b * CC + vd) * NN + nn] = f2b(acc[i] + bv[vd]);
            }
        }
    }
}

// K2: row softmax denominators. E pre-scaled by log2e -> exp2. RSI = 1/rowsum.
__global__ __launch_bounds__(512) void k_rowstats(const ushort* __restrict__ Qt,
        float* __restrict__ RSI) {
    __shared__ ushort Qm[128][36];
    __shared__ float Sred[2][64];
    int bid = (blockIdx.x & 7) * 64 + (blockIdx.x >> 3);
    int b  = bid >> 5;
    int n0 = (bid & 31) << 6;
    int tid = threadIdx.x;
    int w = tid >> 6, l = tid & 63, lr = l & 15, lg = l >> 4;
    int wn = w & 3, wm = w >> 2;
    const ushort* Qtb = Qt + (size_t)b * NN * CQ;
    bf16x8 aq = *(const bf16x8*)&Qtb[(size_t)(n0 + wn * 16 + lr) * CQ + lg * 8];
    int sr = tid >> 2, sc = (tid & 3) * 8;
    uint4 q0 = *(const uint4*)&Qtb[(size_t)sr * CQ + sc];
    float S[4] = {0.f, 0.f, 0.f, 0.f};
    f32x4 zero = {0.f, 0.f, 0.f, 0.f};
    for (int t = 0; t < 16; ++t) {
        __syncthreads();
        *(uint4*)&Qm[sr][sc] = q0;
        __syncthreads();
        if (t < 15)
            q0 = *(const uint4*)&Qtb[(size_t)((t + 1) * 128 + sr) * CQ + sc];
        #pragma unroll
        for (int mi = 0; mi < 4; ++mi) {
            bf16x8 bq = *(const bf16x8*)&Qm[(wm * 4 + mi) * 16 + lr][lg * 8];
            f32x4 e = __builtin_amdgcn_mfma_f32_16x16x32_bf16(aq, bq, zero, 0, 0, 0);
            S[0] += fexp2(e[0]); S[1] += fexp2(e[1]);
            S[2] += fexp2(e[2]); S[3] += fexp2(e[3]);
        }
    }
    #pragma unroll
    for (int d = 1; d < 16; d <<= 1) {
        #pragma unroll
        for (int i = 0; i < 4; ++i) S[i] += __shfl_xor(S[i], d);
    }
    if (lr == 0) {
        #pragma unroll
        for (int i = 0; i < 4; ++i) Sred[wm][wn * 16 + lg * 4 + i] = S[i];
    }
    __syncthreads();
    if (tid < 64)
        RSI[b * NN + n0 + tid] = 1.f / (Sred[0][tid] + Sred[1][tid]);
}

// K3: attn + PV, producer/consumer, m-tile 128, 768 threads, grid 256.
// Producers (waves 0-7): E(t+1) 4 MFMA + softmax + Ws write + V(t+1) staging.
// Consumers (waves 8-11): each owns d-64 x m-64, pacc[2][2], 16 MFMA 32x32x16.
// Vs/Ws double-buffered, ONE barrier per iteration.
__global__ __launch_bounds__(768, 3) void k_attn_pv(const ushort* __restrict__ Qt,
        const ushort* __restrict__ Vb, const float* __restrict__ RSI,
        ushort* __restrict__ XRb) {
    __shared__ ushort Vs[2][128][68];   // [buf][d][n]
    __shared__ ushort Ws[2][128][68];   // [buf][m][n]
    __shared__ float csred[4][128];
    __shared__ float csum[128];
    int bid = (blockIdx.x & 7) * 32 + (blockIdx.x >> 3);   // XCD-chunked swizzle
    int b  = bid >> 4;
    int m0 = (bid & 15) << 7;
    int tid = threadIdx.x;
    int w = tid >> 6, l = tid & 63, lr = l & 15, lg = l >> 4;
    const ushort* Qtb = Qt + (size_t)b * NN * CQ;
    const ushort* Vbb = Vb + (size_t)b * CC * NN;
    const float*  RSb = RSI + (size_t)b * NN;
    f32x4 zero = {0.f, 0.f, 0.f, 0.f};
    bool producer = (w < 8);

    // ---------------- producer state ----------------
    int wn = w & 3, mh = w >> 2;            // n-strip, m-half
    bf16x8 bm[4];
    float cs[4] = {0.f, 0.f, 0.f, 0.f};
    int sv = 0, shv = 0;
    const ushort* vsrc = nullptr;
    bf16x8 aq_nx; float4 rsi_nx;
    // ---------------- consumer state ----------------
    int cw = w - 8;
    int dh = cw >> 1, mh2 = cw & 1;         // d-half, m-half
    int ar = l & 31, kh = l >> 5;
    f32x16 pacc00, pacc01, pacc10, pacc11;

    if (producer) {
        #pragma unroll
        for (int mi = 0; mi < 4; ++mi)
            bm[mi] = *(const bf16x8*)&Qtb[(size_t)(m0 + (mh * 4 + mi) * 16 + lr) * CQ + lg * 8];
        sv = tid >> 2; shv = (tid & 3) * 16;   // V row, 16-col chunk (32 B)
        vsrc = Vbb + (size_t)sv * NN + shv;
        // ---- stage V(0) -> Vs[0] ----
        {
            uint4 v0 = *(const uint4*)(vsrc);
            uint4 v1 = *(const uint4*)(vsrc + 8);
            ushort* dst = &Vs[0][sv][shv];
            *(uint2*)(dst)      = make_uint2(v0.x, v0.y);
            *(uint2*)(dst + 4)  = make_uint2(v0.z, v0.w);
            *(uint2*)(dst + 8)  = make_uint2(v1.x, v1.y);
            *(uint2*)(dst + 12) = make_uint2(v1.z, v1.w);
        }
        // ---- E(0) -> Ws[0] ----
        {
            bf16x8 aq0 = *(const bf16x8*)&Qtb[(size_t)(wn * 16 + lr) * CQ + lg * 8];
            float4 r4 = *(const float4*)&RSb[wn * 16 + lg * 4];
            int nb = wn * 16 + lg * 4;
            #pragma unroll
            for (int mi = 0; mi < 4; ++mi) {
                f32x4 e = __builtin_amdgcn_mfma_f32_16x16x32_bf16(aq0, bm[mi], zero, 0, 0, 0);
                float w0 = fexp2(e[0]) * r4.x;
                float w1 = fexp2(e[1]) * r4.y;
                float w2 = fexp2(e[2]) * r4.z;
                float w3 = fexp2(e[3]) * r4.w;
                cs[mi] += w0 + w1 + w2 + w3;
                *(ushort4*)&Ws[0][(mh * 4 + mi) * 16 + lr][nb] =
                    make_ushort4(f2b(w0), f2b(w1), f2b(w2), f2b(w3));
            }
        }
        // prefetch operands for tile 1
        aq_nx  = *(const bf16x8*)&Qtb[(size_t)(64 + wn * 16 + lr) * CQ + lg * 8];
        rsi_nx = *(const float4*)&RSb[64 + wn * 16 + lg * 4];
    } else {
        #pragma unroll
        for (int r = 0; r < 16; ++r) {
            pacc00[r] = 0.f; pacc01[r] = 0.f; pacc10[r] = 0.f; pacc11[r] = 0.f;
        }
    }
    __syncthreads();
    for (int t = 0; t < 32; ++t) {
        int cur = t & 1;
        if (producer) {
            if (t < 31) {
                int ntn = (t + 1) * 64;
                // issue V(t+1) global loads (in flight under E+exp)
                uint4 v0 = *(const uint4*)(vsrc + ntn);
                uint4 v1 = *(const uint4*)(vsrc + ntn + 8);
                bf16x8 aq = aq_nx;
                float4 r4 = rsi_nx;
                if (t < 30) {
                    int nt2 = (t + 2) * 64;
                    aq_nx  = *(const bf16x8*)&Qtb[(size_t)(nt2 + wn * 16 + lr) * CQ + lg * 8];
                    rsi_nx = *(const float4*)&RSb[nt2 + wn * 16 + lg * 4];
                }
                // ---- E(t+1) -> Ws[cur^1] ----
                int nb = wn * 16 + lg * 4;
                #pragma unroll
                for (int mi = 0; mi < 4; ++mi) {
                    f32x4 e = __builtin_amdgcn_mfma_f32_16x16x32_bf16(aq, bm[mi], zero, 0, 0, 0);
                    float w0 = fexp2(e[0]) * r4.x;
                    float w1 = fexp2(e[1]) * r4.y;
                    float w2 = fexp2(e[2]) * r4.z;
                    float w3 = fexp2(e[3]) * r4.w;
                    cs[mi] += w0 + w1 + w2 + w3;
                    *(ushort4*)&Ws[cur ^ 1][(mh * 4 + mi) * 16 + lr][nb] =
                        make_ushort4(f2b(w0), f2b(w1), f2b(w2), f2b(w3));
                }
                // ---- write V(t+1) -> Vs[cur^1] ----
                ushort* dst = &Vs[cur ^ 1][sv][shv];
                *(uint2*)(dst)      = make_uint2(v0.x, v0.y);
                *(uint2*)(dst + 4)  = make_uint2(v0.z, v0.w);
                *(uint2*)(dst + 8)  = make_uint2(v1.x, v1.y);
                *(uint2*)(dst + 12) = make_uint2(v1.z, v1.w);
            }
        } else {
            // ---- PV on tile t: wave owns d [dh*64,+64) x m [mh2*64,+64) ----
            __builtin_amdgcn_s_setprio(1);
            #pragma unroll
            for (int kk = 0; kk < 4; ++kk) {
                const ushort* vp0 = &Vs[cur][dh * 64 + ar][kk * 16 + kh * 8];
                const ushort* vp1 = &Vs[cur][dh * 64 + 32 + ar][kk * 16 + kh * 8];
                uint2 a0 = *(const uint2*)vp0; uint2 a1 = *(const uint2*)(vp0 + 4);
                uint2 a2 = *(const uint2*)vp1; uint2 a3 = *(const uint2*)(vp1 + 4);
                bf16x8 va0 = as_b8(make_uint4(a0.x, a0.y, a1.x, a1.y));
                bf16x8 va1 = as_b8(make_uint4(a2.x, a2.y, a3.x, a3.y));
                const ushort* wp0 = &Ws[cur][mh2 * 64 + ar][kk * 16 + kh * 8];
                const ushort* wp1 = &Ws[cur][mh2 * 64 + 32 + ar][kk * 16 + kh * 8];
                uint2 b0 = *(const uint2*)wp0; uint2 b1 = *(const uint2*)(wp0 + 4);
                uint2 c0 = *(const uint2*)wp1; uint2 c1 = *(const uint2*)(wp1 + 4);
                bf16x8 wb0 = as_b8(make_uint4(b0.x, b0.y, b1.x, b1.y));
                bf16x8 wb1 = as_b8(make_uint4(c0.x, c0.y, c1.x, c1.y));
                pacc00 = __builtin_amdgcn_mfma_f32_32x32x16_bf16(va0, wb0, pacc00, 0, 0, 0);
                pacc01 = __builtin_amdgcn_mfma_f32_32x32x16_bf16(va0, wb1, pacc01, 0, 0, 0);
                pacc10 = __builtin_amdgcn_mfma_f32_32x32x16_bf16(va1, wb0, pacc10, 0, 0, 0);
                pacc11 = __builtin_amdgcn_mfma_f32_32x32x16_bf16(va1, wb1, pacc11, 0, 0, 0);
            }
            __builtin_amdgcn_s_setprio(0);
        }
        __syncthreads();
    }
    // ---- colsum reduce (producers hold cs for m-subtile (mh*4+mi)*16+lr) ----
    if (producer) {
        #pragma unroll
        for (int mi = 0; mi < 4; ++mi) {
            cs[mi] += __shfl_xor(cs[mi], 16);
            cs[mi] += __shfl_xor(cs[mi], 32);
        }
        if (lg == 0) {
            #pragma unroll
            for (int mi = 0; mi < 4; ++mi)
                csred[wn][(mh * 4 + mi) * 16 + lr] = cs[mi];
        }
    }
    __syncthreads();
    if (tid < 128) {
        float tot = csred[0][tid] + csred[1][tid] + csred[2][tid] + csred[3][tid];
        csum[tid] = 1.f / (1e-9f + tot);
    }
    __syncthreads();
    if (!producer) {
        float inv0 = csum[mh2 * 64 + ar];
        float inv1 = csum[mh2 * 64 + 32 + ar];
        int mA = m0 + mh2 * 64 + ar;
        #pragma unroll
        for (int r = 0; r < 16; ++r) {
            int d0 = dh * 64 + (r & 3) + 8 * (r >> 2) + 4 * kh;
            XRb[(size_t)(b * CC + d0) * NN + mA]          = f2b(pacc00[r] * inv0);
            XRb[(size_t)(b * CC + d0) * NN + mA + 32]     = f2b(pacc01[r] * inv1);
            XRb[(size_t)(b * CC + d0 + 32) * NN + mA]      = f2b(pacc10[r] * inv0);
            XRb[(size_t)(b * CC + d0 + 32) * NN + mA + 32] = f2b(pacc11[r] * inv1);
        }
    }
}

// K4: MFMA final: t = wt @ (x - XR); out = x + relu(t*fA + fB).
__global__ __launch_bounds__(256) void k_final(const float* __restrict__ x,
        const ushort* __restrict__ XRb, const float* __restrict__ wt,
        const float* __restrict__ bt, const float* __restrict__ gamma,
        const float* __restrict__ beta, const float* __restrict__ bn_mean,
        const float* __restrict__ bn_var, float* __restrict__ out) {
    __shared__ ushort Wl[128][136];
    __shared__ ushort Us[64][136];   // [n][c] bf16
    __shared__ float fAl[128], fBl[128];
    int bid = (blockIdx.x & 7) * 64 + (blockIdx.x >> 3);
    int b  = bid >> 5;
    int n0 = (bid & 31) << 6;
    int tid = threadIdx.x;
    #pragma unroll
    for (int k = 0; k < 16; ++k) {
        int idx = k * 256 + tid;
        int r = idx >> 5, c4 = (idx & 31) << 2;
        float4 w4 = *(const float4*)&wt[r * 128 + c4];
        *(ushort4*)&Wl[r][c4] = make_ushort4(f2b(w4.x), f2b(w4.y), f2b(w4.z), f2b(w4.w));
    }
    if (tid < 128) {
        float A = gamma[tid] * rsqrtf(bn_var[tid] + 1e-5f);
        fAl[tid] = A;
        fBl[tid] = (bt[tid] - bn_mean[tid]) * A + beta[tid];
    }
    const float*  xb  = x   + (size_t)b * CC * NN;
    const ushort* xrb = XRb + (size_t)b * CC * NN;
    for (int idx = tid; idx < 2048; idx += 256) {
        int c = idx >> 4, n4 = (idx & 15) << 2;
        float4 xv = *(const float4*)&xb[c * NN + n0 + n4];
        ushort4 rv = *(const ushort4*)&xrb[c * NN + n0 + n4];
        Us[n4][c]     = f2b(xv.x - b2f(rv.x));
        Us[n4 + 1][c] = f2b(xv.y - b2f(rv.y));
        Us[n4 + 2][c] = f2b(xv.z - b2f(rv.z));
        Us[n4 + 3][c] = f2b(xv.w - b2f(rv.w));
    }
    __syncthreads();
    int w = tid >> 6, l = tid & 63, lr = l & 15, lg = l >> 4;
    f32x4 zero = {0.f, 0.f, 0.f, 0.f};
    int nn = n0 + w * 16 + lr;
    for (int dt = 0; dt < 8; ++dt) {
        f32x4 acc = zero;
        #pragma unroll
        for (int k = 0; k < 4; ++k) {
            bf16x8 a  = *(const bf16x8*)&Wl[dt * 16 + lr][k * 32 + lg * 8];
            bf16x8 bx = *(const bf16x8*)&Us[w * 16 + lr][k * 32 + lg * 8];
            acc = __builtin_amdgcn_mfma_f32_16x16x32_bf16(a, bx, acc, 0, 0, 0);
        }
        #pragma unroll
        for (int i = 0; i < 4; ++i) {
            int r = dt * 16 + lg * 4 + i;
            float t = acc[i] * fAl[r] + fBl[r];
            t = fmaxf(t, 0.f);
            out[(size_t)(b * CC + r) * NN + nn] = xb[r * NN + nn] + t;
        }
    }
}

extern "C" void kernel_launch(void* const* d_in, const int* in_sizes, int n_in,
                              void* d_out, int out_size, void* d_ws, size_t ws_size,
                              hipStream_t stream) {
    const float* x       = (const float*)d_in[0];
    const float* wq      = (const float*)d_in[1];
    const float* wv      = (const float*)d_in[2];
    const float* bv      = (const float*)d_in[3];
    const float* wt      = (const float*)d_in[4];
    const float* bt      = (const float*)d_in[5];
    const float* gamma   = (const float*)d_in[6];
    const float* beta    = (const float*)d_in[7];
    const float* bn_mean = (const float*)d_in[8];
    const float* bn_var  = (const float*)d_in[9];
    float* out = (float*)d_out;
    float* ws  = (float*)d_ws;

    ushort* Qt   = (ushort*)ws;
    ushort* Vbp  = (ushort*)(ws + OFF_VB);
    ushort* XRb  = (ushort*)(ws + OFF_XRB);
    float*  RSI  = ws + OFF_RSI;

    k_proj<<<BB * 32, 256, 0, stream>>>(x, wq, wv, bv, Qt, Vbp);
    k_rowstats<<<BB * 32, 512, 0, stream>>>(Qt, RSI);
    k_attn_pv<<<BB * 16, 768, 0, stream>>>(Qt, Vbp, RSI, XRb);
    k_final<<<BB * 32, 256, 0, stream>>>(x, XRb, wt, bt, gamma, beta, bn_mean, bn_var, out);
}

// Round 14
// 62.496 us; speedup vs baseline: 1.3625x; 1.0718x over previous
//
#include <hip/hip_runtime.h>
#include <hip/hip_bf16.h>
#include <math.h>

#define BB 16
#define CC 128
#define NN 2048
#define CQ 32   // C/4

typedef __attribute__((ext_vector_type(8))) short bf16x8;
typedef __attribute__((ext_vector_type(4))) float f32x4;
typedef __attribute__((ext_vector_type(16))) float f32x16;

__device__ __forceinline__ ushort f2b(float f) {
    __hip_bfloat16 h = __float2bfloat16(f);
    return *reinterpret_cast<ushort*>(&h);
}
__device__ __forceinline__ float b2f(ushort u) {
    union { unsigned u; float f; } v; v.u = ((unsigned)u) << 16;
    return v.f;
}
__device__ __forceinline__ bf16x8 as_b8(uint4 u) {
    union { uint4 u; bf16x8 b; } v; v.u = u; return v.b;
}
__device__ __forceinline__ bf16x8 as_b8_2(uint2 a, uint2 b) {
    return as_b8(make_uint4(a.x, a.y, b.x, b.y));
}
__device__ __forceinline__ float fexp2(float x) {
    return __builtin_amdgcn_exp2f(x);   // v_exp_f32: 2^x
}

// ---------------- workspace layout (float granularity offsets) ----------------
// Qt  : bf16 [B][N][32]   off 0          (wq pre-scaled by sqrt(log2 e))
// Vb  : bf16 [B][128][N]  off 524,288
// RSI : f32  [B][N]       off 4,718,592
#define OFF_VB  524288
#define OFF_RSI 4718592

#define QSCALE 1.2011224087864498f   // sqrt(log2(e)); E comes out scaled by log2(e)

// K1: MFMA projection. Qt[b,n,d] (d<32, scaled), Vb[b,d,n] = wv.x + bv.
__global__ __launch_bounds__(256) void k_proj(const float* __restrict__ x,
        const float* __restrict__ wq, const float* __restrict__ wv,
        const float* __restrict__ bv, ushort* __restrict__ Qt, ushort* __restrict__ Vb) {
    __shared__ ushort Wl[160][136];
    __shared__ ushort Xs[64][136];   // [n][c] bf16
    int bid = (blockIdx.x & 7) * 64 + (blockIdx.x >> 3);   // XCD-chunked swizzle
    int b  = bid >> 5;
    int n0 = (bid & 31) << 6;
    int tid = threadIdx.x;
    #pragma unroll
    for (int k = 0; k < 20; ++k) {
        int idx = k * 256 + tid;
        int r = idx >> 5, c4 = (idx & 31) << 2;
        const float* srcw = (r < 32) ? (wq + r * 128 + c4) : (wv + (r - 32) * 128 + c4);
        float4 w4 = *(const float4*)srcw;
        float s = (r < 32) ? QSCALE : 1.0f;
        *(ushort4*)&Wl[r][c4] = make_ushort4(f2b(w4.x * s), f2b(w4.y * s),
                                             f2b(w4.z * s), f2b(w4.w * s));
    }
    const float* xb = x + (size_t)b * CC * NN;
    for (int idx = tid; idx < 2048; idx += 256) {
        int c = idx >> 4, n4 = (idx & 15) << 2;
        float4 xv = *(const float4*)&xb[c * NN + n0 + n4];
        Xs[n4][c]     = f2b(xv.x);
        Xs[n4 + 1][c] = f2b(xv.y);
        Xs[n4 + 2][c] = f2b(xv.z);
        Xs[n4 + 3][c] = f2b(xv.w);
    }
    __syncthreads();
    int w = tid >> 6, l = tid & 63, lr = l & 15, lg = l >> 4;
    f32x4 zero = {0.f, 0.f, 0.f, 0.f};
    int nn = n0 + w * 16 + lr;
    for (int dt = 0; dt < 10; ++dt) {
        f32x4 acc = zero;
        #pragma unroll
        for (int k = 0; k < 4; ++k) {
            bf16x8 a  = *(const bf16x8*)&Wl[dt * 16 + lr][k * 32 + lg * 8];
            bf16x8 bx = *(const bf16x8*)&Xs[w * 16 + lr][k * 32 + lg * 8];
            acc = __builtin_amdgcn_mfma_f32_16x16x32_bf16(a, bx, acc, 0, 0, 0);
        }
        if (dt < 2) {
            ushort4 p = make_ushort4(f2b(acc[0]), f2b(acc[1]), f2b(acc[2]), f2b(acc[3]));
            *(ushort4*)&Qt[(size_t)(b * NN + nn) * CQ + dt * 16 + lg * 4] = p;
        } else {
            #pragma unroll
            for (int i = 0; i < 4; ++i) {
                int vd = (dt - 2) * 16 + lg * 4 + i;
                Vb[(size_t)(b * CC + vd) * NN + nn] = f2b(acc[i] + bv[vd]);
            }
        }
    }
}

// K2: row softmax denominators. E pre-scaled by log2e -> exp2. RSI = 1/rowsum.
__global__ __launch_bounds__(512) void k_rowstats(const ushort* __restrict__ Qt,
        float* __restrict__ RSI) {
    __shared__ ushort Qm[128][36];
    __shared__ float Sred[2][64];
    int bid = (blockIdx.x & 7) * 64 + (blockIdx.x >> 3);
    int b  = bid >> 5;
    int n0 = (bid & 31) << 6;
    int tid = threadIdx.x;
    int w = tid >> 6, l = tid & 63, lr = l & 15, lg = l >> 4;
    int wn = w & 3, wm = w >> 2;
    const ushort* Qtb = Qt + (size_t)b * NN * CQ;
    bf16x8 aq = *(const bf16x8*)&Qtb[(size_t)(n0 + wn * 16 + lr) * CQ + lg * 8];
    int sr = tid >> 2, sc = (tid & 3) * 8;
    uint4 q0 = *(const uint4*)&Qtb[(size_t)sr * CQ + sc];
    float S[4] = {0.f, 0.f, 0.f, 0.f};
    f32x4 zero = {0.f, 0.f, 0.f, 0.f};
    for (int t = 0; t < 16; ++t) {
        __syncthreads();
        *(uint4*)&Qm[sr][sc] = q0;
        __syncthreads();
        if (t < 15)
            q0 = *(const uint4*)&Qtb[(size_t)((t + 1) * 128 + sr) * CQ + sc];
        #pragma unroll
        for (int mi = 0; mi < 4; ++mi) {
            bf16x8 bq = *(const bf16x8*)&Qm[(wm * 4 + mi) * 16 + lr][lg * 8];
            f32x4 e = __builtin_amdgcn_mfma_f32_16x16x32_bf16(aq, bq, zero, 0, 0, 0);
            S[0] += fexp2(e[0]); S[1] += fexp2(e[1]);
            S[2] += fexp2(e[2]); S[3] += fexp2(e[3]);
        }
    }
    #pragma unroll
    for (int d = 1; d < 16; d <<= 1) {
        #pragma unroll
        for (int i = 0; i < 4; ++i) S[i] += __shfl_xor(S[i], d);
    }
    if (lr == 0) {
        #pragma unroll
        for (int i = 0; i < 4; ++i) Sred[wm][wn * 16 + lg * 4 + i] = S[i];
    }
    __syncthreads();
    if (tid < 64)
        RSI[b * NN + n0 + tid] = 1.f / (Sred[0][tid] + Sred[1][tid]);
}

// K3: attn + PV + FUSED FINAL. m-tile 128, 768 thr, grid 256.
// Producers (w 0-7): E(t+1) + softmax + Ws write + V staging.
// Consumers (w 8-11): PV 32x32x16, pacc[2][2] quadrants.
// Epilogue: Us[m][c] = bf16(x - XR) in LDS (alias Vs), wt GEMM, BN+ReLU+residual.
__global__ __launch_bounds__(768, 3) void k_attn_pv(const ushort* __restrict__ Qt,
        const ushort* __restrict__ Vb, const float* __restrict__ RSI,
        const float* __restrict__ x, const float* __restrict__ wt,
        const float* __restrict__ bt, const float* __restrict__ gamma,
        const float* __restrict__ beta, const float* __restrict__ bn_mean,
        const float* __restrict__ bn_var, float* __restrict__ out) {
    __shared__ ushort Vs[2][128][68];   // [buf][d][n]; epilogue: Us[m][c] stride 132
    __shared__ ushort Ws[2][128][68];   // [buf][m][n]
    __shared__ ushort wtl[16896];       // wt bf16 [128][132]
    __shared__ float csred[4][128];
    __shared__ float csum[128];
    __shared__ float fAl[128], fBl[128];
    int bid = (blockIdx.x & 7) * 32 + (blockIdx.x >> 3);   // XCD-chunked swizzle
    int b  = bid >> 4;
    int m0 = (bid & 15) << 7;
    int tid = threadIdx.x;
    int w = tid >> 6, l = tid & 63, lr = l & 15, lg = l >> 4;
    const ushort* Qtb = Qt + (size_t)b * NN * CQ;
    const ushort* Vbb = Vb + (size_t)b * CC * NN;
    const float*  RSb = RSI + (size_t)b * NN;
    const float*  xb  = x   + (size_t)b * CC * NN;
    float*        outb = out + (size_t)b * CC * NN;
    f32x4 zero = {0.f, 0.f, 0.f, 0.f};
    bool producer = (w < 8);

    // ---- stage wt -> wtl (bf16, stride 132) + BN constants ----
    for (int idx = tid; idx < 4096; idx += 768) {
        int r = idx >> 5, c4 = (idx & 31) << 2;
        float4 w4 = *(const float4*)&wt[r * 128 + c4];
        *(ushort4*)&wtl[r * 132 + c4] =
            make_ushort4(f2b(w4.x), f2b(w4.y), f2b(w4.z), f2b(w4.w));
    }
    if (tid < 128) {
        float A = gamma[tid] * rsqrtf(bn_var[tid] + 1e-5f);
        fAl[tid] = A;
        fBl[tid] = (bt[tid] - bn_mean[tid]) * A + beta[tid];
    }

    // ---------------- producer state ----------------
    int wn = w & 3, mh = w >> 2;            // n-strip, m-half
    bf16x8 bm[4];
    float cs[4] = {0.f, 0.f, 0.f, 0.f};
    int sv = 0, shv = 0;
    const ushort* vsrc = nullptr;
    bf16x8 aq_nx; float4 rsi_nx;
    // ---------------- consumer state ----------------
    int cw = w - 8;
    int dh = cw >> 1, mh2 = cw & 1;         // d-half, m-half
    int ar = l & 31, kh = l >> 5;
    f32x16 pacc00, pacc01, pacc10, pacc11;

    if (producer) {
        #pragma unroll
        for (int mi = 0; mi < 4; ++mi)
            bm[mi] = *(const bf16x8*)&Qtb[(size_t)(m0 + (mh * 4 + mi) * 16 + lr) * CQ + lg * 8];
        sv = tid >> 2; shv = (tid & 3) * 16;   // V row, 16-col chunk
        vsrc = Vbb + (size_t)sv * NN + shv;
        {
            uint4 v0 = *(const uint4*)(vsrc);
            uint4 v1 = *(const uint4*)(vsrc + 8);
            ushort* dst = &Vs[0][sv][shv];
            *(uint2*)(dst)      = make_uint2(v0.x, v0.y);
            *(uint2*)(dst + 4)  = make_uint2(v0.z, v0.w);
            *(uint2*)(dst + 8)  = make_uint2(v1.x, v1.y);
            *(uint2*)(dst + 12) = make_uint2(v1.z, v1.w);
        }
        {
            bf16x8 aq0 = *(const bf16x8*)&Qtb[(size_t)(wn * 16 + lr) * CQ + lg * 8];
            float4 r4 = *(const float4*)&RSb[wn * 16 + lg * 4];
            int nb = wn * 16 + lg * 4;
            #pragma unroll
            for (int mi = 0; mi < 4; ++mi) {
                f32x4 e = __builtin_amdgcn_mfma_f32_16x16x32_bf16(aq0, bm[mi], zero, 0, 0, 0);
                float w0 = fexp2(e[0]) * r4.x;
                float w1 = fexp2(e[1]) * r4.y;
                float w2 = fexp2(e[2]) * r4.z;
                float w3 = fexp2(e[3]) * r4.w;
                cs[mi] += w0 + w1 + w2 + w3;
                *(ushort4*)&Ws[0][(mh * 4 + mi) * 16 + lr][nb] =
                    make_ushort4(f2b(w0), f2b(w1), f2b(w2), f2b(w3));
            }
        }
        aq_nx  = *(const bf16x8*)&Qtb[(size_t)(64 + wn * 16 + lr) * CQ + lg * 8];
        rsi_nx = *(const float4*)&RSb[64 + wn * 16 + lg * 4];
    } else {
        #pragma unroll
        for (int r = 0; r < 16; ++r) {
            pacc00[r] = 0.f; pacc01[r] = 0.f; pacc10[r] = 0.f; pacc11[r] = 0.f;
        }
    }
    __syncthreads();
    for (int t = 0; t < 32; ++t) {
        int cur = t & 1;
        if (producer) {
            if (t < 31) {
                int ntn = (t + 1) * 64;
                uint4 v0 = *(const uint4*)(vsrc + ntn);
                uint4 v1 = *(const uint4*)(vsrc + ntn + 8);
                bf16x8 aq = aq_nx;
                float4 r4 = rsi_nx;
                if (t < 30) {
                    int nt2 = (t + 2) * 64;
                    aq_nx  = *(const bf16x8*)&Qtb[(size_t)(nt2 + wn * 16 + lr) * CQ + lg * 8];
                    rsi_nx = *(const float4*)&RSb[nt2 + wn * 16 + lg * 4];
                }
                int nb = wn * 16 + lg * 4;
                #pragma unroll
                for (int mi = 0; mi < 4; ++mi) {
                    f32x4 e = __builtin_amdgcn_mfma_f32_16x16x32_bf16(aq, bm[mi], zero, 0, 0, 0);
                    float w0 = fexp2(e[0]) * r4.x;
                    float w1 = fexp2(e[1]) * r4.y;
                    float w2 = fexp2(e[2]) * r4.z;
                    float w3 = fexp2(e[3]) * r4.w;
                    cs[mi] += w0 + w1 + w2 + w3;
                    *(ushort4*)&Ws[cur ^ 1][(mh * 4 + mi) * 16 + lr][nb] =
                        make_ushort4(f2b(w0), f2b(w1), f2b(w2), f2b(w3));
                }
                ushort* dst = &Vs[cur ^ 1][sv][shv];
                *(uint2*)(dst)      = make_uint2(v0.x, v0.y);
                *(uint2*)(dst + 4)  = make_uint2(v0.z, v0.w);
                *(uint2*)(dst + 8)  = make_uint2(v1.x, v1.y);
                *(uint2*)(dst + 12) = make_uint2(v1.z, v1.w);
            }
        } else {
            __builtin_amdgcn_s_setprio(1);
            #pragma unroll
            for (int kk = 0; kk < 4; ++kk) {
                const ushort* vp0 = &Vs[cur][dh * 64 + ar][kk * 16 + kh * 8];
                const ushort* vp1 = &Vs[cur][dh * 64 + 32 + ar][kk * 16 + kh * 8];
                uint2 a0 = *(const uint2*)vp0; uint2 a1 = *(const uint2*)(vp0 + 4);
                uint2 a2 = *(const uint2*)vp1; uint2 a3 = *(const uint2*)(vp1 + 4);
                bf16x8 va0 = as_b8_2(a0, a1);
                bf16x8 va1 = as_b8_2(a2, a3);
                const ushort* wp0 = &Ws[cur][mh2 * 64 + ar][kk * 16 + kh * 8];
                const ushort* wp1 = &Ws[cur][mh2 * 64 + 32 + ar][kk * 16 + kh * 8];
                uint2 b0 = *(const uint2*)wp0; uint2 b1 = *(const uint2*)(wp0 + 4);
                uint2 c0 = *(const uint2*)wp1; uint2 c1 = *(const uint2*)(wp1 + 4);
                bf16x8 wb0 = as_b8_2(b0, b1);
                bf16x8 wb1 = as_b8_2(c0, c1);
                pacc00 = __builtin_amdgcn_mfma_f32_32x32x16_bf16(va0, wb0, pacc00, 0, 0, 0);
                pacc01 = __builtin_amdgcn_mfma_f32_32x32x16_bf16(va0, wb1, pacc01, 0, 0, 0);
                pacc10 = __builtin_amdgcn_mfma_f32_32x32x16_bf16(va1, wb0, pacc10, 0, 0, 0);
                pacc11 = __builtin_amdgcn_mfma_f32_32x32x16_bf16(va1, wb1, pacc11, 0, 0, 0);
            }
            __builtin_amdgcn_s_setprio(0);
        }
        __syncthreads();
    }
    // ---- colsum reduce ----
    if (producer) {
        #pragma unroll
        for (int mi = 0; mi < 4; ++mi) {
            cs[mi] += __shfl_xor(cs[mi], 16);
            cs[mi] += __shfl_xor(cs[mi], 32);
        }
        if (lg == 0) {
            #pragma unroll
            for (int mi = 0; mi < 4; ++mi)
                csred[wn][(mh * 4 + mi) * 16 + lr] = cs[mi];
        }
    }
    __syncthreads();
    if (tid < 128) {
        float tot = csred[0][tid] + csred[1][tid] + csred[2][tid] + csred[3][tid];
        csum[tid] = 1.f / (1e-9f + tot);
    }
    __syncthreads();
    // ---- consumers: Us[m][c] = bf16(x - XR), aliased on Vs, stride 132 ----
    ushort* UsP = &Vs[0][0][0];
    if (!producer) {
        float inv0 = csum[mh2 * 64 + ar];
        float inv1 = csum[mh2 * 64 + 32 + ar];
        int mA = m0 + mh2 * 64 + ar;          // global m
        int mL = mh2 * 64 + ar;               // local m
        #pragma unroll
        for (int g = 0; g < 4; ++g) {
            int db = dh * 64 + 8 * g + 4 * kh;   // 4 consecutive d at db..db+3
            ushort4 u00, u01, u10, u11;
            #pragma unroll
            for (int j = 0; j < 4; ++j) {
                int r = 4 * g + j;
                float x00 = xb[(size_t)(db + j) * NN + mA];
                float x01 = xb[(size_t)(db + j) * NN + mA + 32];
                float x10 = xb[(size_t)(db + 32 + j) * NN + mA];
                float x11 = xb[(size_t)(db + 32 + j) * NN + mA + 32];
                ((ushort*)&u00)[j] = f2b(x00 - pacc00[r] * inv0);
                ((ushort*)&u01)[j] = f2b(x01 - pacc01[r] * inv1);
                ((ushort*)&u10)[j] = f2b(x10 - pacc10[r] * inv0);
                ((ushort*)&u11)[j] = f2b(x11 - pacc11[r] * inv1);
            }
            *(ushort4*)&UsP[mL * 132 + db]             = u00;
            *(ushort4*)&UsP[(mL + 32) * 132 + db]      = u01;
            *(ushort4*)&UsP[mL * 132 + db + 32]        = u10;
            *(ushort4*)&UsP[(mL + 32) * 132 + db + 32] = u11;
        }
    }
    __syncthreads();
    // ---- all waves: t = wt @ Us^T; out = x + relu(t*fA + fB) ----
    for (int tile = w; tile < 16; tile += 12) {
        int rt = tile >> 2, mt = tile & 3;
        f32x16 acc;
        #pragma unroll
        for (int r = 0; r < 16; ++r) acc[r] = 0.f;
        #pragma unroll
        for (int kk = 0; kk < 8; ++kk) {
            const ushort* ap = &wtl[(rt * 32 + ar) * 132 + kk * 16 + kh * 8];
            uint2 a0 = *(const uint2*)ap; uint2 a1 = *(const uint2*)(ap + 4);
            const ushort* bp = &UsP[(mt * 32 + ar) * 132 + kk * 16 + kh * 8];
            uint2 b0 = *(const uint2*)bp; uint2 b1 = *(const uint2*)(bp + 4);
            acc = __builtin_amdgcn_mfma_f32_32x32x16_bf16(
                as_b8_2(a0, a1), as_b8_2(b0, b1), acc, 0, 0, 0);
        }
        int m = m0 + mt * 32 + ar;
        #pragma unroll
        for (int g = 0; g < 4; ++g) {
            #pragma unroll
            for (int j = 0; j < 4; ++j) {
                int r = rt * 32 + j + 8 * g + 4 * kh;
                float t = acc[4 * g + j] * fAl[r] + fBl[r];
                t = fmaxf(t, 0.f);
                outb[(size_t)r * NN + m] = xb[(size_t)r * NN + m] + t;
            }
        }
    }
}

extern "C" void kernel_launch(void* const* d_in, const int* in_sizes, int n_in,
                              void* d_out, int out_size, void* d_ws, size_t ws_size,
                              hipStream_t stream) {
    const float* x       = (const float*)d_in[0];
    const float* wq      = (const float*)d_in[1];
    const float* wv      = (const float*)d_in[2];
    const float* bv      = (const float*)d_in[3];
    const float* wt      = (const float*)d_in[4];
    const float* bt      = (const float*)d_in[5];
    const float* gamma   = (const float*)d_in[6];
    const float* beta    = (const float*)d_in[7];
    const float* bn_mean = (const float*)d_in[8];
    const float* bn_var  = (const float*)d_in[9];
    float* out = (float*)d_out;
    float* ws  = (float*)d_ws;

    ushort* Qt   = (ushort*)ws;
    ushort* Vbp  = (ushort*)(ws + OFF_VB);
    float*  RSI  = ws + OFF_RSI;

    k_proj<<<BB * 32, 256, 0, stream>>>(x, wq, wv, bv, Qt, Vbp);
    k_rowstats<<<BB * 32, 512, 0, stream>>>(Qt, RSI);
    k_attn_pv<<<BB * 16, 768, 0, stream>>>(Qt, Vbp, RSI, x, wt, bt, gamma, beta,
                                           bn_mean, bn_var, out);
}